// Round 16
// baseline (312.117 us; speedup 1.0000x reference)
//
#include <hip/hip_runtime.h>
#include <math.h>
#include <stdint.h>

typedef __attribute__((ext_vector_type(8))) short short8v;
typedef __attribute__((ext_vector_type(4))) float float4v;

__device__ __forceinline__ float bf2f(unsigned short u) {
  return __uint_as_float((unsigned int)u << 16);
}
__device__ __forceinline__ unsigned short f2bf(float f) {   // RNE
  unsigned int u = __float_as_uint(f);
  unsigned int r = (u + 0x7FFFu + ((u >> 16) & 1u)) >> 16;
  return (unsigned short)r;
}
__device__ __forceinline__ float exp_lrelu(float x) {
  x = x > 0.f ? x : 0.2f * x;
  return expf(x);       // softmax shift-invariant: segment-max skipped
}

typedef __attribute__((address_space(3))) void lds_void;
typedef const __attribute__((address_space(1))) void glb_void;
__device__ __forceinline__ void gload_lds16(const void* g, void* l) {
  __builtin_amdgcn_global_load_lds((glb_void*)g, (lds_void*)l, 16, 0, 0);
}

// ---------------- weight prep (all 3 weights in one dispatch) ----------------
__device__ __forceinline__ void wprep_one(const float* W, unsigned short* Wh,
                                          int t, int K, int Nw)
{
  int i = t & 7;
  int lane = (t >> 3) & 63;
  int frag = t >> 9;
  int ktiles = K >> 5;
  int n_tile = frag / ktiles, k_tile = frag - n_tile * ktiles;
  int k = k_tile * 32 + ((lane >> 4) << 3) + i;
  int n = (n_tile << 4) + (lane & 15);
  Wh[t] = f2bf(W[(size_t)k * Nw + n]);
}

__global__ void wprep_all_kernel(const float* __restrict__ W1, unsigned short* __restrict__ w1h,
                                 const float* __restrict__ W2, unsigned short* __restrict__ w2h,
                                 const float* __restrict__ W3, unsigned short* __restrict__ w3h)
{
  int t = blockIdx.x * 256 + threadIdx.x;
  const int s1 = 128 * 256, s2 = 256 * 256, s3 = 256 * 64;
  if (t < s1) { wprep_one(W1, w1h, t, 128, 256); return; }
  t -= s1;
  if (t < s2) { wprep_one(W2, w2h, t, 256, 256); return; }
  t -= s2;
  if (t < s3) { wprep_one(W3, w3h, t, 256, 64); }
}

// ---------------- A-side: x fp32 -> bf16 (RNE) ----------------
__global__ __launch_bounds__(256) void split_kernel(const float* __restrict__ in,
    unsigned short* __restrict__ hi, size_t n4)
{
  size_t i0 = (size_t)blockIdx.x * 256 + threadIdx.x;
  size_t stride = (size_t)gridDim.x * 256;
  for (size_t idx = i0; idx < n4; idx += stride) {
    float4 v = ((const float4*)in)[idx];
    ushort4 h;
    h.x = f2bf(v.x); h.y = f2bf(v.y); h.z = f2bf(v.z); h.w = f2bf(v.w);
    ((ushort4*)hi)[idx] = h;
  }
}

// BN + ELU -> bf16 (RNE), reading bf16 act
__global__ __launch_bounds__(256) void bnsplit_kernel(const unsigned short* __restrict__ act,
    const float* __restrict__ scale, const float* __restrict__ shift,
    unsigned short* __restrict__ hi, size_t nchunks)
{
  size_t i0 = (size_t)blockIdx.x * 256 + threadIdx.x;
  size_t stride = (size_t)gridDim.x * 256;
  for (size_t idx = i0; idx < nchunks; idx += stride) {
    ushort4 u = ((const ushort4*)act)[idx];
    int f = (int)((idx * 4) & 255);
    float4 sc = *(const float4*)(scale + f);
    float4 sh = *(const float4*)(shift + f);
    float v0 = fmaf(bf2f(u.x), sc.x, sh.x);
    float v1 = fmaf(bf2f(u.y), sc.y, sh.y);
    float v2 = fmaf(bf2f(u.z), sc.z, sh.z);
    float v3 = fmaf(bf2f(u.w), sc.w, sh.w);
    v0 = v0 > 0.f ? v0 : expm1f(v0);
    v1 = v1 > 0.f ? v1 : expm1f(v1);
    v2 = v2 > 0.f ? v2 : expm1f(v2);
    v3 = v3 > 0.f ? v3 : expm1f(v3);
    ushort4 h;
    h.x = f2bf(v0); h.y = f2bf(v1); h.z = f2bf(v2); h.w = f2bf(v3);
    ((ushort4*)hi)[idx] = h;
  }
}

// ---------------- single-bf16 MFMA GEMM + fused al epilogue, LDS-staged A ----------------
template<int MI, int WM, int WN, int KSTEPS, int HEADS>
__global__ __launch_bounds__(128) void gemm_al(
    const unsigned short* __restrict__ Ah, const unsigned short* __restrict__ Bh,
    const float* __restrict__ a_s, const float* __restrict__ a_d,
    unsigned short* __restrict__ C, float* __restrict__ al_s, float* __restrict__ al_d,
    int M)
{
  constexpr int NWAVES = WM * WN;            // 2
  constexpr int BM = WM * MI * 16;           // 64
  constexpr int TILEB = BM * 64 * 2;         // 8 KB per buffer
  constexpr int Nw = HEADS * 64;
  constexpr int K = KSTEPS * 64;
  constexpr int KT32 = KSTEPS * 2;
  __shared__ __align__(16) unsigned char smem[2][TILEB];

  const int wid = threadIdx.x >> 6, lane = threadIdx.x & 63;
  const int wm = wid / WN, wn = wid % WN;
  const int gn = blockIdx.y * WN + wn;       // global 64-col tile index
  const int m0 = blockIdx.x * BM;
  const int n0 = gn * 64;
  const int ar = lane & 15;
  const int cchunk = lane >> 4;
  const int ntile0 = n0 >> 4;

  float4v acc[MI][4];
#pragma unroll
  for (int mi = 0; mi < MI; ++mi)
#pragma unroll
    for (int ni = 0; ni < 4; ++ni)
      acc[mi][ni] = (float4v){0.f, 0.f, 0.f, 0.f};

  auto stage = [&](int buf, int ks) {
#pragma unroll
    for (int c = wid; c < 8; c += NWAVES) {
      const unsigned short* gp = Ah + (size_t)(m0 + lane) * K + ks * 64 + c * 8;
      gload_lds16(gp, &smem[buf][c * 1024 + lane * 16]);
    }
  };

  stage(0, 0);
  int cur = 0;
  for (int ks = 0; ks < KSTEPS; ++ks) {
    __syncthreads();   // stage(cur) complete; buffers handed off
    short8v bh[2][4];
#pragma unroll
    for (int hh = 0; hh < 2; ++hh)
#pragma unroll
      for (int ni = 0; ni < 4; ++ni) {
        int kt = ks * 2 + hh;
        size_t off = (((size_t)(ntile0 + ni) * KT32 + kt) * 64 + lane) * 8;
        bh[hh][ni] = *(const short8v*)(Bh + off);
      }
    if (ks + 1 < KSTEPS) stage(cur ^ 1, ks + 1);
    short8v ah[2][MI];
#pragma unroll
    for (int hh = 0; hh < 2; ++hh)
#pragma unroll
      for (int mi = 0; mi < MI; ++mi) {
        int row = wm * MI * 16 + mi * 16 + ar;
        int c = hh * 4 + cchunk;
        ah[hh][mi] = *(const short8v*)&smem[cur][c * 1024 + row * 16];
      }
#pragma unroll
    for (int hh = 0; hh < 2; ++hh)
#pragma unroll
      for (int mi = 0; mi < MI; ++mi)
#pragma unroll
        for (int ni = 0; ni < 4; ++ni)
          acc[mi][ni] = __builtin_amdgcn_mfma_f32_16x16x32_bf16(ah[hh][mi], bh[hh][ni], acc[mi][ni], 0, 0, 0);
    cur ^= 1;
  }

  const int cc = lane & 15;
#pragma unroll
  for (int mi = 0; mi < MI; ++mi) {
    int rowb = m0 + wm * MI * 16 + mi * 16 + ((lane >> 4) << 2);
#pragma unroll
    for (int r = 0; r < 4; ++r) {
      int row = rowb + r;
      if (row < M) {
#pragma unroll
        for (int ni = 0; ni < 4; ++ni)
          C[(size_t)row * Nw + n0 + ni * 16 + cc] = f2bf(acc[mi][ni][r]);
      }
    }
  }

  // fused attention-logit epilogue (bf16-rounded h = downstream values)
  const int head = (HEADS == 4) ? gn : 0;
  float as_[4], ad_[4];
#pragma unroll
  for (int ni = 0; ni < 4; ++ni) {
    as_[ni] = a_s[head * 64 + ni * 16 + cc];
    ad_[ni] = a_d[head * 64 + ni * 16 + cc];
  }
#pragma unroll
  for (int mi = 0; mi < MI; ++mi) {
#pragma unroll
    for (int r = 0; r < 4; ++r) {
      float h0 = bf2f(f2bf(acc[mi][0][r]));
      float h1 = bf2f(f2bf(acc[mi][1][r]));
      float h2 = bf2f(f2bf(acc[mi][2][r]));
      float h3 = bf2f(f2bf(acc[mi][3][r]));
      float ps = h0 * as_[0] + h1 * as_[1] + h2 * as_[2] + h3 * as_[3];
      float pd = h0 * ad_[0] + h1 * ad_[1] + h2 * ad_[2] + h3 * ad_[3];
#pragma unroll
      for (int off = 1; off < 16; off <<= 1) {
        ps += __shfl_xor(ps, off);
        pd += __shfl_xor(pd, off);
      }
      int row = m0 + wm * MI * 16 + mi * 16 + ((lane >> 4) << 2) + r;
      if (cc == 0 && row < M) {
        al_s[row * HEADS + head] = ps;
        al_d[row * HEADS + head] = pd;
      }
    }
  }
}

// ---------------- CSR build ----------------
__global__ void count_kernel(const int* __restrict__ dst, int E, int Etot, int* __restrict__ counts)
{
  int e = blockIdx.x * 256 + threadIdx.x;
  if (e >= Etot) return;
  int d = (e < E) ? dst[e] : (e - E);
  atomicAdd(&counts[d], 1);
}

__global__ void block_sum_kernel(const int* __restrict__ counts, int N, int* __restrict__ bsums)
{
  __shared__ int sd[256];
  int i = blockIdx.x * 256 + threadIdx.x;
  sd[threadIdx.x] = (i < N) ? counts[i] : 0;
  __syncthreads();
  for (int off = 128; off; off >>= 1) {
    if (threadIdx.x < off) sd[threadIdx.x] += sd[threadIdx.x + off];
    __syncthreads();
  }
  if (threadIdx.x == 0) bsums[blockIdx.x] = sd[0];
}

__global__ void scan_bsums_kernel(int* bsums, int nb)
{
  __shared__ int sd[256];
  int t = threadIdx.x;
  int v = (t < nb) ? bsums[t] : 0;
  sd[t] = v;
  __syncthreads();
  for (int off = 1; off < 256; off <<= 1) {
    int x = (t >= off) ? sd[t - off] : 0;
    __syncthreads();
    sd[t] += x;
    __syncthreads();
  }
  if (t < nb) bsums[t] = sd[t] - v;  // exclusive
}

__global__ void scan_write_kernel(const int* __restrict__ counts, int N,
                                  const int* __restrict__ bsums, int* __restrict__ rowStart, int Etot)
{
  __shared__ int sd[256];
  int i = blockIdx.x * 256 + threadIdx.x;
  int v = (i < N) ? counts[i] : 0;
  sd[threadIdx.x] = v;
  __syncthreads();
  for (int off = 1; off < 256; off <<= 1) {
    int x = (threadIdx.x >= off) ? sd[threadIdx.x - off] : 0;
    __syncthreads();
    sd[threadIdx.x] += x;
    __syncthreads();
  }
  if (i < N) rowStart[i] = bsums[blockIdx.x] + sd[threadIdx.x] - v;  // exclusive
  if (i == N - 1) rowStart[N] = Etot;
}

__global__ void fill_kernel(const int* __restrict__ src, const int* __restrict__ dst,
                            int E, int Etot, const int* __restrict__ rowStart,
                            int* __restrict__ cursor, int* __restrict__ csrSrc)
{
  int e = blockIdx.x * 256 + threadIdx.x;
  if (e >= Etot) return;
  int s, d;
  if (e < E) { s = src[e]; d = dst[e]; } else { s = d = e - E; }
  int pos = rowStart[d] + atomicAdd(&cursor[d], 1);
  csrSrc[pos] = s;
}

// ---------------- fused aggregation, 4-head layers (bf16 out) ----------------
__global__ __launch_bounds__(256) void aggregate_fused4(
    const unsigned short* __restrict__ h16,
    const float* __restrict__ als, const float* __restrict__ ald,
    const int* __restrict__ csrSrc, const int* __restrict__ rowStart,
    unsigned short* __restrict__ outp, int N)
{
  __shared__ float ldsW[4][256];
  const int wl = threadIdx.x >> 6;
  int wid = blockIdx.x * 4 + wl;
  if (wid >= N) return;
  const int lane = threadIdx.x & 63;
  const int head = lane >> 4;
  const int start = rowStart[wid], end = rowStart[wid + 1];

  float4 adv = ((const float4*)ald)[wid];
  float acc[4] = {};
  float wsum = 0.f;

  for (int base = start; base < end; base += 64) {
    int cnt = end - base; if (cnt > 64) cnt = 64;
    int s_l = 0;
    if (lane < cnt) {
      s_l = csrSrc[base + lane];
      float4 av = ((const float4*)als)[s_l];
      float4 w4;
      w4.x = exp_lrelu(av.x + adv.x);
      w4.y = exp_lrelu(av.y + adv.y);
      w4.z = exp_lrelu(av.z + adv.z);
      w4.w = exp_lrelu(av.w + adv.w);
      *(float4*)&ldsW[wl][lane * 4] = w4;
    }
    int i = 0;
    for (; i + 4 <= cnt; i += 4) {
      int s0 = __shfl(s_l, i);
      int s1 = __shfl(s_l, i + 1);
      int s2 = __shfl(s_l, i + 2);
      int s3 = __shfl(s_l, i + 3);
      float w0 = ldsW[wl][(i + 0) * 4 + head];
      float w1 = ldsW[wl][(i + 1) * 4 + head];
      float w2 = ldsW[wl][(i + 2) * 4 + head];
      float w3 = ldsW[wl][(i + 3) * 4 + head];
      ushort4 r0 = ((const ushort4*)(h16 + (size_t)s0 * 256))[lane];
      ushort4 r1 = ((const ushort4*)(h16 + (size_t)s1 * 256))[lane];
      ushort4 r2 = ((const ushort4*)(h16 + (size_t)s2 * 256))[lane];
      ushort4 r3 = ((const ushort4*)(h16 + (size_t)s3 * 256))[lane];
      wsum += (w0 + w1) + (w2 + w3);
      acc[0] = fmaf(w0, bf2f(r0.x), acc[0]);
      acc[1] = fmaf(w0, bf2f(r0.y), acc[1]);
      acc[2] = fmaf(w0, bf2f(r0.z), acc[2]);
      acc[3] = fmaf(w0, bf2f(r0.w), acc[3]);
      acc[0] = fmaf(w1, bf2f(r1.x), acc[0]);
      acc[1] = fmaf(w1, bf2f(r1.y), acc[1]);
      acc[2] = fmaf(w1, bf2f(r1.z), acc[2]);
      acc[3] = fmaf(w1, bf2f(r1.w), acc[3]);
      acc[0] = fmaf(w2, bf2f(r2.x), acc[0]);
      acc[1] = fmaf(w2, bf2f(r2.y), acc[1]);
      acc[2] = fmaf(w2, bf2f(r2.z), acc[2]);
      acc[3] = fmaf(w2, bf2f(r2.w), acc[3]);
      acc[0] = fmaf(w3, bf2f(r3.x), acc[0]);
      acc[1] = fmaf(w3, bf2f(r3.y), acc[1]);
      acc[2] = fmaf(w3, bf2f(r3.z), acc[2]);
      acc[3] = fmaf(w3, bf2f(r3.w), acc[3]);
    }
    for (; i < cnt; ++i) {
      int s0 = __shfl(s_l, i);
      float w0 = ldsW[wl][i * 4 + head];
      wsum += w0;
      ushort4 r0 = ((const ushort4*)(h16 + (size_t)s0 * 256))[lane];
      acc[0] = fmaf(w0, bf2f(r0.x), acc[0]);
      acc[1] = fmaf(w0, bf2f(r0.y), acc[1]);
      acc[2] = fmaf(w0, bf2f(r0.z), acc[2]);
      acc[3] = fmaf(w0, bf2f(r0.w), acc[3]);
    }
  }

  float inv = 1.0f / wsum;
  ushort4 o;
  o.x = f2bf(acc[0] * inv); o.y = f2bf(acc[1] * inv);
  o.z = f2bf(acc[2] * inv); o.w = f2bf(acc[3] * inv);
  ((ushort4*)(outp + (size_t)wid * 256))[lane] = o;
}

// ---------------- layer-3 aggregation + bias + ELU + fused MLP head ----------------
// Grid-stride over nodes: weights staged once per block, copied to per-lane regs.
__global__ __launch_bounds__(256) void agg3_mlp_kernel(
    const unsigned short* __restrict__ h16,
    const float* __restrict__ als, const float* __restrict__ ald,
    const int* __restrict__ csrSrc, const int* __restrict__ rowStart,
    const float* __restrict__ b3,
    const float* __restrict__ fw1, const float* __restrict__ fb1,
    const float* __restrict__ fw2, const float* __restrict__ fb2,
    float* __restrict__ out, int N)
{
  __shared__ float ldsW[4][64];
  __shared__ float w1s[64][32];
  __shared__ float mrow[4][64];
  const int t = threadIdx.x;
  for (int i = t; i < 2048; i += 256) w1s[i >> 5][i & 31] = fw1[i];
  __syncthreads();            // weights staged before any wave proceeds

  const int wl = t >> 6, lane = t & 63;
  const int j = lane & 31, col = lane >> 5;
  // per-lane register copies (hoisted out of the node loop)
  float w1c[64];
#pragma unroll
  for (int k = 0; k < 64; ++k) w1c[k] = w1s[k][j];
  const float b1v = fb1[j];
  const float w2v = fw2[j * 2 + col];
  const float b2v = fb2[col];
  const float b3v = b3[lane];

  const int nwaves = (int)gridDim.x * 4;
  for (int wid = blockIdx.x * 4 + wl; wid < N; wid += nwaves) {
    const int start = rowStart[wid], end = rowStart[wid + 1];
    const float ad0 = ald[wid];

    float acc = 0.f, wsum = 0.f;
    for (int base = start; base < end; base += 64) {
      int cnt = end - base; if (cnt > 64) cnt = 64;
      int s_l = 0;
      if (lane < cnt) {
        s_l = csrSrc[base + lane];
        ldsW[wl][lane] = exp_lrelu(als[s_l] + ad0);
      }
      int i = 0;
      for (; i + 4 <= cnt; i += 4) {
        int s0 = __shfl(s_l, i);
        int s1 = __shfl(s_l, i + 1);
        int s2 = __shfl(s_l, i + 2);
        int s3 = __shfl(s_l, i + 3);
        float w0 = ldsW[wl][i + 0];
        float w1 = ldsW[wl][i + 1];
        float w2 = ldsW[wl][i + 2];
        float w3 = ldsW[wl][i + 3];
        unsigned short r0 = h16[(size_t)s0 * 64 + lane];
        unsigned short r1 = h16[(size_t)s1 * 64 + lane];
        unsigned short r2 = h16[(size_t)s2 * 64 + lane];
        unsigned short r3 = h16[(size_t)s3 * 64 + lane];
        wsum += (w0 + w1) + (w2 + w3);
        acc = fmaf(w0, bf2f(r0), acc);
        acc = fmaf(w1, bf2f(r1), acc);
        acc = fmaf(w2, bf2f(r2), acc);
        acc = fmaf(w3, bf2f(r3), acc);
      }
      for (; i < cnt; ++i) {
        int s0 = __shfl(s_l, i);
        float w0 = ldsW[wl][i];
        wsum += w0;
        unsigned short r0 = h16[(size_t)s0 * 64 + lane];
        acc = fmaf(w0, bf2f(r0), acc);
      }
    }
    float o = acc / wsum + b3v;
    o = o > 0.f ? o : expm1f(o);

    // in-wave MLP: lane j owns hidden unit j; col = lane>>5
    mrow[wl][lane] = o;
    float hid = b1v;
#pragma unroll
    for (int k = 0; k < 64; ++k)
      hid = fmaf(mrow[wl][k], w1c[k], hid);   // wave-uniform LDS broadcast
    hid = fmaxf(hid, 0.f);
    float p = hid * w2v;
#pragma unroll
    for (int off = 1; off < 32; off <<= 1) p += __shfl_xor(p, off);
    if (j == 0) out[(size_t)wid * 2 + col] = p + b2v;
  }
}

// ---------------- batch norm stats (deterministic partials, two dispatches) ----
__global__ __launch_bounds__(256) void bn_stats_kernel(const unsigned short* __restrict__ x, int N,
                                float* __restrict__ partials)   // [128][512]
{
  const int wid = threadIdx.x >> 6, lane = threadIdx.x & 63;
  const int gw = blockIdx.x * 4 + wid;
  const int tw = gridDim.x * 4;
  float4 s = make_float4(0.f, 0.f, 0.f, 0.f);
  float4 q = make_float4(0.f, 0.f, 0.f, 0.f);
#pragma unroll 4
  for (int r = gw; r < N; r += tw) {
    ushort4 u = ((const ushort4*)(x + (size_t)r * 256))[lane];
    float v0 = bf2f(u.x), v1 = bf2f(u.y), v2 = bf2f(u.z), v3 = bf2f(u.w);
    s.x += v0; s.y += v1; s.z += v2; s.w += v3;
    q.x = fmaf(v0, v0, q.x); q.y = fmaf(v1, v1, q.y);
    q.z = fmaf(v2, v2, q.z); q.w = fmaf(v3, v3, q.w);
  }
  __shared__ float ls[4][512];
  *(float4*)&ls[wid][lane * 4] = s;
  *(float4*)&ls[wid][256 + lane * 4] = q;
  __syncthreads();
  const int t = threadIdx.x;
  float a = ls[0][t] + ls[1][t] + ls[2][t] + ls[3][t];
  float b = ls[0][t + 256] + ls[1][t + 256] + ls[2][t + 256] + ls[3][t + 256];
  partials[blockIdx.x * 512 + t] = a;
  partials[blockIdx.x * 512 + 256 + t] = b;
}

__global__ void bn_final_kernel(const float* __restrict__ partials, int nblk,
                                const float* __restrict__ g, const float* __restrict__ be,
                                int N, float* __restrict__ scale, float* __restrict__ shift)
{
  int f = threadIdx.x;
  float s = 0.f, q = 0.f;
#pragma unroll 8
  for (int b = 0; b < nblk; ++b) {
    s += partials[b * 512 + f];
    q += partials[b * 512 + 256 + f];
  }
  float mu = s / N;
  float var = q / N - mu * mu;
  float rs = rsqrtf(var + 1e-5f);
  float sc = g[f] * rs;
  scale[f] = sc;
  shift[f] = be[f] - mu * sc;
}

// ---------------- host ----------------
extern "C" void kernel_launch(void* const* d_in, const int* in_sizes, int n_in,
                              void* d_out, int out_size, void* d_ws, size_t ws_size,
                              hipStream_t stream)
{
  const float* x   = (const float*)d_in[0];
  const int*   ei  = (const int*)d_in[1];
  const float* W1  = (const float*)d_in[2];
  const float* a1s = (const float*)d_in[3];
  const float* a1d = (const float*)d_in[4];
  const float* W2  = (const float*)d_in[6];
  const float* a2s = (const float*)d_in[7];
  const float* a2d = (const float*)d_in[8];
  const float* W3  = (const float*)d_in[10];
  const float* a3s = (const float*)d_in[11];
  const float* a3d = (const float*)d_in[12];
  const float* b3  = (const float*)d_in[13];
  const float* g1  = (const float*)d_in[14];
  const float* be1 = (const float*)d_in[15];
  const float* g2  = (const float*)d_in[16];
  const float* be2 = (const float*)d_in[17];
  const float* fw1 = (const float*)d_in[18];
  const float* fb1 = (const float*)d_in[19];
  const float* fw2 = (const float*)d_in[20];
  const float* fb2 = (const float*)d_in[21];
  float* out = (float*)d_out;

  const int F = 128;
  const int N = in_sizes[0] / F;
  const int E = in_sizes[1] / 2;
  const int Etot = E + N;
  const int* srcIdx = ei;
  const int* dstIdx = ei + E;

  char* w = (char*)d_ws;
  auto alloc = [&](size_t bytes) -> void* {
    void* p = (void*)w;
    w += (bytes + 255) & ~(size_t)255;
    return p;
  };
  unsigned short* h16  = (unsigned short*)alloc((size_t)N * 256 * 2);
  unsigned short* act16= (unsigned short*)alloc((size_t)N * 256 * 2);
  unsigned short* aBf  = (unsigned short*)alloc((size_t)N * 256 * 2);
  float* als     = (float*)alloc((size_t)N * 4 * 4);
  float* ald     = (float*)alloc((size_t)N * 4 * 4);
  const size_t cntPad = ((size_t)N * 4 + 255) & ~(size_t)255;
  int*   counts  = (int*)alloc((size_t)N * 4);
  int*   cursor  = (int*)alloc((size_t)N * 4);     // contiguous after counts
  int*   rowStart= (int*)alloc((size_t)(N + 1) * 4);
  int*   csrSrc  = (int*)alloc((size_t)Etot * 4);
  int*   bsums   = (int*)alloc((size_t)((N + 255) / 256) * 4);
  float* partials= (float*)alloc((size_t)128 * 512 * 4);
  float* scale1  = (float*)alloc(256 * 4);
  float* shift1  = (float*)alloc(256 * 4);
  float* scale2  = (float*)alloc(256 * 4);
  float* shift2  = (float*)alloc(256 * 4);
  unsigned short* w1h = (unsigned short*)alloc((size_t)128 * 256 * 2);
  unsigned short* w2h = (unsigned short*)alloc((size_t)256 * 256 * 2);
  unsigned short* w3h = (unsigned short*)alloc((size_t)256 * 64 * 2);
  (void)alloc(65536);   // slack for OOB staging reads of last GEMM block

  const int nb = (N + 255) / 256;
  const int ebk = (Etot + 255) / 256;
  const int aggBlocks = (N + 3) / 4;

  // ---- weight prep (one dispatch for all three) ----
  const int wtot = 128 * 256 + 256 * 256 + 256 * 64;
  wprep_all_kernel<<<(wtot + 255) / 256, 256, 0, stream>>>(W1, w1h, W2, w2h, W3, w3h);

  // ---- CSR build ----
  hipMemsetAsync(counts, 0, cntPad + (size_t)N * 4, stream);   // counts + cursor
  count_kernel<<<ebk, 256, 0, stream>>>(dstIdx, E, Etot, counts);
  block_sum_kernel<<<nb, 256, 0, stream>>>(counts, N, bsums);
  scan_bsums_kernel<<<1, 256, 0, stream>>>(bsums, nb);
  scan_write_kernel<<<nb, 256, 0, stream>>>(counts, N, bsums, rowStart, Etot);
  fill_kernel<<<ebk, 256, 0, stream>>>(srcIdx, dstIdx, E, Etot, rowStart, cursor, csrSrc);

  dim3 g12((N + 63) / 64, 2);      // layers 1,2: MI=4,WM=1,WN=2 -> BM=64,BN=128
  dim3 g3((N + 63) / 64, 1);       // layer 3:   MI=2,WM=2,WN=1 -> BM=64,BN=64

  // ---- GAT layer 1 ----
  split_kernel<<<2048, 256, 0, stream>>>(x, aBf, (size_t)N * 128 / 4);
  gemm_al<4, 1, 2, 2, 4><<<g12, 128, 0, stream>>>(aBf, w1h, a1s, a1d, h16, als, ald, N);
  aggregate_fused4<<<aggBlocks, 256, 0, stream>>>(h16, als, ald, csrSrc, rowStart, act16, N);
  bn_stats_kernel<<<128, 256, 0, stream>>>(act16, N, partials);
  bn_final_kernel<<<1, 256, 0, stream>>>(partials, 128, g1, be1, N, scale1, shift1);

  // ---- GAT layer 2 ----
  bnsplit_kernel<<<2048, 256, 0, stream>>>(act16, scale1, shift1, aBf, (size_t)N * 64);
  gemm_al<4, 1, 2, 4, 4><<<g12, 128, 0, stream>>>(aBf, w2h, a2s, a2d, h16, als, ald, N);
  aggregate_fused4<<<aggBlocks, 256, 0, stream>>>(h16, als, ald, csrSrc, rowStart, act16, N);
  bn_stats_kernel<<<128, 256, 0, stream>>>(act16, N, partials);
  bn_final_kernel<<<1, 256, 0, stream>>>(partials, 128, g2, be2, N, scale2, shift2);

  // ---- GAT layer 3 + fused MLP head ----
  bnsplit_kernel<<<2048, 256, 0, stream>>>(act16, scale2, shift2, aBf, (size_t)N * 64);
  gemm_al<2, 2, 1, 4, 1><<<g3, 128, 0, stream>>>(aBf, w3h, a3s, a3d, h16, als, ald, N);
  agg3_mlp_kernel<<<2560, 256, 0, stream>>>(h16, als, ald, csrSrc, rowStart,
                                            b3, fw1, fb1, fw2, fb2, out, N);
}

// Round 17
// 309.841 us; speedup vs baseline: 1.0073x; 1.0073x over previous
//
#include <hip/hip_runtime.h>
#include <math.h>
#include <stdint.h>

typedef __attribute__((ext_vector_type(8))) short short8v;
typedef __attribute__((ext_vector_type(4))) float float4v;

__device__ __forceinline__ float bf2f(unsigned short u) {
  return __uint_as_float((unsigned int)u << 16);
}
__device__ __forceinline__ unsigned short f2bf(float f) {   // RNE
  unsigned int u = __float_as_uint(f);
  unsigned int r = (u + 0x7FFFu + ((u >> 16) & 1u)) >> 16;
  return (unsigned short)r;
}
__device__ __forceinline__ float exp_lrelu(float x) {
  x = x > 0.f ? x : 0.2f * x;
  return expf(x);       // softmax shift-invariant: segment-max skipped
}

typedef __attribute__((address_space(3))) void lds_void;
typedef const __attribute__((address_space(1))) void glb_void;
__device__ __forceinline__ void gload_lds16(const void* g, void* l) {
  __builtin_amdgcn_global_load_lds((glb_void*)g, (lds_void*)l, 16, 0, 0);
}

// ---------------- weight prep (all 3 weights in one dispatch) ----------------
__device__ __forceinline__ void wprep_one(const float* W, unsigned short* Wh,
                                          int t, int K, int Nw)
{
  int i = t & 7;
  int lane = (t >> 3) & 63;
  int frag = t >> 9;
  int ktiles = K >> 5;
  int n_tile = frag / ktiles, k_tile = frag - n_tile * ktiles;
  int k = k_tile * 32 + ((lane >> 4) << 3) + i;
  int n = (n_tile << 4) + (lane & 15);
  Wh[t] = f2bf(W[(size_t)k * Nw + n]);
}

__global__ void wprep_all_kernel(const float* __restrict__ W1, unsigned short* __restrict__ w1h,
                                 const float* __restrict__ W2, unsigned short* __restrict__ w2h,
                                 const float* __restrict__ W3, unsigned short* __restrict__ w3h)
{
  int t = blockIdx.x * 256 + threadIdx.x;
  const int s1 = 128 * 256, s2 = 256 * 256, s3 = 256 * 64;
  if (t < s1) { wprep_one(W1, w1h, t, 128, 256); return; }
  t -= s1;
  if (t < s2) { wprep_one(W2, w2h, t, 256, 256); return; }
  t -= s2;
  if (t < s3) { wprep_one(W3, w3h, t, 256, 64); }
}

// ---------------- A-side: x fp32 -> bf16 (RNE) ----------------
__global__ __launch_bounds__(256) void split_kernel(const float* __restrict__ in,
    unsigned short* __restrict__ hi, size_t n4)
{
  size_t i0 = (size_t)blockIdx.x * 256 + threadIdx.x;
  size_t stride = (size_t)gridDim.x * 256;
  for (size_t idx = i0; idx < n4; idx += stride) {
    float4 v = ((const float4*)in)[idx];
    ushort4 h;
    h.x = f2bf(v.x); h.y = f2bf(v.y); h.z = f2bf(v.z); h.w = f2bf(v.w);
    ((ushort4*)hi)[idx] = h;
  }
}

// BN + ELU -> bf16 (RNE), reading bf16 act
__global__ __launch_bounds__(256) void bnsplit_kernel(const unsigned short* __restrict__ act,
    const float* __restrict__ scale, const float* __restrict__ shift,
    unsigned short* __restrict__ hi, size_t nchunks)
{
  size_t i0 = (size_t)blockIdx.x * 256 + threadIdx.x;
  size_t stride = (size_t)gridDim.x * 256;
  for (size_t idx = i0; idx < nchunks; idx += stride) {
    ushort4 u = ((const ushort4*)act)[idx];
    int f = (int)((idx * 4) & 255);
    float4 sc = *(const float4*)(scale + f);
    float4 sh = *(const float4*)(shift + f);
    float v0 = fmaf(bf2f(u.x), sc.x, sh.x);
    float v1 = fmaf(bf2f(u.y), sc.y, sh.y);
    float v2 = fmaf(bf2f(u.z), sc.z, sh.z);
    float v3 = fmaf(bf2f(u.w), sc.w, sh.w);
    v0 = v0 > 0.f ? v0 : expm1f(v0);
    v1 = v1 > 0.f ? v1 : expm1f(v1);
    v2 = v2 > 0.f ? v2 : expm1f(v2);
    v3 = v3 > 0.f ? v3 : expm1f(v3);
    ushort4 h;
    h.x = f2bf(v0); h.y = f2bf(v1); h.z = f2bf(v2); h.w = f2bf(v3);
    ((ushort4*)hi)[idx] = h;
  }
}

// ---------------- single-bf16 MFMA GEMM + fused al epilogue, LDS-staged A ----------------
template<int MI, int WM, int WN, int KSTEPS, int HEADS>
__global__ __launch_bounds__(128) void gemm_al(
    const unsigned short* __restrict__ Ah, const unsigned short* __restrict__ Bh,
    const float* __restrict__ a_s, const float* __restrict__ a_d,
    unsigned short* __restrict__ C, float* __restrict__ al_s, float* __restrict__ al_d,
    int M)
{
  constexpr int NWAVES = WM * WN;            // 2
  constexpr int BM = WM * MI * 16;           // 64
  constexpr int TILEB = BM * 64 * 2;         // 8 KB per buffer
  constexpr int Nw = HEADS * 64;
  constexpr int K = KSTEPS * 64;
  constexpr int KT32 = KSTEPS * 2;
  __shared__ __align__(16) unsigned char smem[2][TILEB];

  const int wid = threadIdx.x >> 6, lane = threadIdx.x & 63;
  const int wm = wid / WN, wn = wid % WN;
  const int gn = blockIdx.y * WN + wn;       // global 64-col tile index
  const int m0 = blockIdx.x * BM;
  const int n0 = gn * 64;
  const int ar = lane & 15;
  const int cchunk = lane >> 4;
  const int ntile0 = n0 >> 4;

  float4v acc[MI][4];
#pragma unroll
  for (int mi = 0; mi < MI; ++mi)
#pragma unroll
    for (int ni = 0; ni < 4; ++ni)
      acc[mi][ni] = (float4v){0.f, 0.f, 0.f, 0.f};

  auto stage = [&](int buf, int ks) {
#pragma unroll
    for (int c = wid; c < 8; c += NWAVES) {
      const unsigned short* gp = Ah + (size_t)(m0 + lane) * K + ks * 64 + c * 8;
      gload_lds16(gp, &smem[buf][c * 1024 + lane * 16]);
    }
  };

  stage(0, 0);
  int cur = 0;
  for (int ks = 0; ks < KSTEPS; ++ks) {
    __syncthreads();   // stage(cur) complete; buffers handed off
    short8v bh[2][4];
#pragma unroll
    for (int hh = 0; hh < 2; ++hh)
#pragma unroll
      for (int ni = 0; ni < 4; ++ni) {
        int kt = ks * 2 + hh;
        size_t off = (((size_t)(ntile0 + ni) * KT32 + kt) * 64 + lane) * 8;
        bh[hh][ni] = *(const short8v*)(Bh + off);
      }
    if (ks + 1 < KSTEPS) stage(cur ^ 1, ks + 1);
    short8v ah[2][MI];
#pragma unroll
    for (int hh = 0; hh < 2; ++hh)
#pragma unroll
      for (int mi = 0; mi < MI; ++mi) {
        int row = wm * MI * 16 + mi * 16 + ar;
        int c = hh * 4 + cchunk;
        ah[hh][mi] = *(const short8v*)&smem[cur][c * 1024 + row * 16];
      }
#pragma unroll
    for (int hh = 0; hh < 2; ++hh)
#pragma unroll
      for (int mi = 0; mi < MI; ++mi)
#pragma unroll
        for (int ni = 0; ni < 4; ++ni)
          acc[mi][ni] = __builtin_amdgcn_mfma_f32_16x16x32_bf16(ah[hh][mi], bh[hh][ni], acc[mi][ni], 0, 0, 0);
    cur ^= 1;
  }

  const int cc = lane & 15;
#pragma unroll
  for (int mi = 0; mi < MI; ++mi) {
    int rowb = m0 + wm * MI * 16 + mi * 16 + ((lane >> 4) << 2);
#pragma unroll
    for (int r = 0; r < 4; ++r) {
      int row = rowb + r;
      if (row < M) {
#pragma unroll
        for (int ni = 0; ni < 4; ++ni)
          C[(size_t)row * Nw + n0 + ni * 16 + cc] = f2bf(acc[mi][ni][r]);
      }
    }
  }

  // fused attention-logit epilogue (bf16-rounded h = downstream values)
  const int head = (HEADS == 4) ? gn : 0;
  float as_[4], ad_[4];
#pragma unroll
  for (int ni = 0; ni < 4; ++ni) {
    as_[ni] = a_s[head * 64 + ni * 16 + cc];
    ad_[ni] = a_d[head * 64 + ni * 16 + cc];
  }
#pragma unroll
  for (int mi = 0; mi < MI; ++mi) {
#pragma unroll
    for (int r = 0; r < 4; ++r) {
      float h0 = bf2f(f2bf(acc[mi][0][r]));
      float h1 = bf2f(f2bf(acc[mi][1][r]));
      float h2 = bf2f(f2bf(acc[mi][2][r]));
      float h3 = bf2f(f2bf(acc[mi][3][r]));
      float ps = h0 * as_[0] + h1 * as_[1] + h2 * as_[2] + h3 * as_[3];
      float pd = h0 * ad_[0] + h1 * ad_[1] + h2 * ad_[2] + h3 * ad_[3];
#pragma unroll
      for (int off = 1; off < 16; off <<= 1) {
        ps += __shfl_xor(ps, off);
        pd += __shfl_xor(pd, off);
      }
      int row = m0 + wm * MI * 16 + mi * 16 + ((lane >> 4) << 2) + r;
      if (cc == 0 && row < M) {
        al_s[row * HEADS + head] = ps;
        al_d[row * HEADS + head] = pd;
      }
    }
  }
}

// ---------------- CSR build ----------------
__global__ void count_kernel(const int* __restrict__ dst, int E, int Etot, int* __restrict__ counts)
{
  int e = blockIdx.x * 256 + threadIdx.x;
  if (e >= Etot) return;
  int d = (e < E) ? dst[e] : (e - E);
  atomicAdd(&counts[d], 1);
}

__global__ void block_sum_kernel(const int* __restrict__ counts, int N, int* __restrict__ bsums)
{
  __shared__ int sd[256];
  int i = blockIdx.x * 256 + threadIdx.x;
  sd[threadIdx.x] = (i < N) ? counts[i] : 0;
  __syncthreads();
  for (int off = 128; off; off >>= 1) {
    if (threadIdx.x < off) sd[threadIdx.x] += sd[threadIdx.x + off];
    __syncthreads();
  }
  if (threadIdx.x == 0) bsums[blockIdx.x] = sd[0];
}

__global__ void scan_bsums_kernel(int* bsums, int nb)
{
  __shared__ int sd[256];
  int t = threadIdx.x;
  int v = (t < nb) ? bsums[t] : 0;
  sd[t] = v;
  __syncthreads();
  for (int off = 1; off < 256; off <<= 1) {
    int x = (t >= off) ? sd[t - off] : 0;
    __syncthreads();
    sd[t] += x;
    __syncthreads();
  }
  if (t < nb) bsums[t] = sd[t] - v;  // exclusive
}

__global__ void scan_write_kernel(const int* __restrict__ counts, int N,
                                  const int* __restrict__ bsums, int* __restrict__ rowStart, int Etot)
{
  __shared__ int sd[256];
  int i = blockIdx.x * 256 + threadIdx.x;
  int v = (i < N) ? counts[i] : 0;
  sd[threadIdx.x] = v;
  __syncthreads();
  for (int off = 1; off < 256; off <<= 1) {
    int x = (threadIdx.x >= off) ? sd[threadIdx.x - off] : 0;
    __syncthreads();
    sd[threadIdx.x] += x;
    __syncthreads();
  }
  if (i < N) rowStart[i] = bsums[blockIdx.x] + sd[threadIdx.x] - v;  // exclusive
  if (i == N - 1) rowStart[N] = Etot;
}

__global__ void fill_kernel(const int* __restrict__ src, const int* __restrict__ dst,
                            int E, int Etot, const int* __restrict__ rowStart,
                            int* __restrict__ cursor, int* __restrict__ csrSrc)
{
  int e = blockIdx.x * 256 + threadIdx.x;
  if (e >= Etot) return;
  int s, d;
  if (e < E) { s = src[e]; d = dst[e]; } else { s = d = e - E; }
  int pos = rowStart[d] + atomicAdd(&cursor[d], 1);
  csrSrc[pos] = s;
}

// ---------------- fused aggregation, 4-head layers (bf16 out) ----------------
// 2 edges per memory instruction: lane = 32*sub + c; lane reads 16B (8 feats) of edge i+sub.
__global__ __launch_bounds__(256) void aggregate_fused4(
    const unsigned short* __restrict__ h16,
    const float* __restrict__ als, const float* __restrict__ ald,
    const int* __restrict__ csrSrc, const int* __restrict__ rowStart,
    unsigned short* __restrict__ outp, int N)
{
  __shared__ float ldsW[4][256];
  const int wl = threadIdx.x >> 6;
  int wid = blockIdx.x * 4 + wl;
  if (wid >= N) return;
  const int lane = threadIdx.x & 63;
  const int sub = lane >> 5, c = lane & 31;   // feature slice c*8..c*8+7
  const int head = c >> 3;
  const int start = rowStart[wid], end = rowStart[wid + 1];

  float4 adv = ((const float4*)ald)[wid];
  float acc[8] = {};
  float wsum = 0.f;

  for (int base = start; base < end; base += 64) {
    int cnt = end - base; if (cnt > 64) cnt = 64;
    int s_l = 0;
    if (lane < cnt) {
      s_l = csrSrc[base + lane];
      float4 av = ((const float4*)als)[s_l];
      float4 w4;
      w4.x = exp_lrelu(av.x + adv.x);
      w4.y = exp_lrelu(av.y + adv.y);
      w4.z = exp_lrelu(av.z + adv.z);
      w4.w = exp_lrelu(av.w + adv.w);
      *(float4*)&ldsW[wl][lane * 4] = w4;
    }
    for (int i = 0; i < cnt; i += 2) {
      int e = i + sub;                         // <= 63
      int s = __shfl(s_l, e);                  // s_l==0 for lanes>=cnt -> safe row 0
      float w = (e < cnt) ? ldsW[wl][e * 4 + head] : 0.f;
      short8v r = *(const short8v*)(h16 + (size_t)s * 256 + c * 8);
      wsum += w;
#pragma unroll
      for (int q = 0; q < 8; ++q)
        acc[q] = fmaf(w, bf2f((unsigned short)r[q]), acc[q]);
    }
  }
  // merge the two sub-groups (partner lane has same c)
#pragma unroll
  for (int q = 0; q < 8; ++q) acc[q] += __shfl_xor(acc[q], 32);
  wsum += __shfl_xor(wsum, 32);

  if (sub == 0) {
    float inv = 1.0f / wsum;
    short8v o;
#pragma unroll
    for (int q = 0; q < 8; ++q) o[q] = (short)f2bf(acc[q] * inv);
    *(short8v*)(outp + (size_t)wid * 256 + c * 8) = o;
  }
}

// ---------------- layer-3 aggregation + bias + ELU + fused MLP head ----------------
// 4 edges per memory instruction: lane = 16*sub + c; lane reads 8B (4 feats) of edge i+sub.
__global__ __launch_bounds__(256) void agg3_mlp_kernel(
    const unsigned short* __restrict__ h16,
    const float* __restrict__ als, const float* __restrict__ ald,
    const int* __restrict__ csrSrc, const int* __restrict__ rowStart,
    const float* __restrict__ b3,
    const float* __restrict__ fw1, const float* __restrict__ fb1,
    const float* __restrict__ fw2, const float* __restrict__ fb2,
    float* __restrict__ out, int N)
{
  __shared__ float ldsW[4][64];
  __shared__ float w1s[64][32];
  __shared__ float mrow[4][64];
  const int t = threadIdx.x;
  for (int i = t; i < 2048; i += 256) w1s[i >> 5][i & 31] = fw1[i];
  __syncthreads();            // weights staged before any wave proceeds

  const int wl = t >> 6, lane = t & 63;
  const int sub = lane >> 4, c = lane & 15;   // feature slice c*4..c*4+3
  const int j = lane & 31, col = lane >> 5;
  const float b1v = fb1[j];
  const float w2v = fw2[j * 2 + col];
  const float b2v = fb2[col];
  const float4 b3q = ((const float4*)b3)[c];

  int wid = blockIdx.x * 4 + wl;
  if (wid >= N) return;       // after the only block barrier — safe
  const int start = rowStart[wid], end = rowStart[wid + 1];
  const float ad0 = ald[wid];

  float a0 = 0.f, a1 = 0.f, a2 = 0.f, a3 = 0.f, wsum = 0.f;
  for (int base = start; base < end; base += 64) {
    int cnt = end - base; if (cnt > 64) cnt = 64;
    int s_l = 0;
    if (lane < cnt) {
      s_l = csrSrc[base + lane];
      ldsW[wl][lane] = exp_lrelu(als[s_l] + ad0);
    }
    for (int i = 0; i < cnt; i += 4) {
      int e = i + sub;                         // <= 63
      int s = __shfl(s_l, e);                  // safe: 0 for invalid
      float w = (e < cnt) ? ldsW[wl][e] : 0.f;
      ushort4 r = ((const ushort4*)(h16 + (size_t)s * 64))[c];
      wsum += w;
      a0 = fmaf(w, bf2f(r.x), a0);
      a1 = fmaf(w, bf2f(r.y), a1);
      a2 = fmaf(w, bf2f(r.z), a2);
      a3 = fmaf(w, bf2f(r.w), a3);
    }
  }
  // merge the four sub-groups (partner lanes share c)
  a0 += __shfl_xor(a0, 16); a1 += __shfl_xor(a1, 16);
  a2 += __shfl_xor(a2, 16); a3 += __shfl_xor(a3, 16);
  wsum += __shfl_xor(wsum, 16);
  a0 += __shfl_xor(a0, 32); a1 += __shfl_xor(a1, 32);
  a2 += __shfl_xor(a2, 32); a3 += __shfl_xor(a3, 32);
  wsum += __shfl_xor(wsum, 32);

  float inv = 1.0f / wsum;
  float o0 = fmaf(a0, inv, 0.f) + b3q.x;
  float o1 = fmaf(a1, inv, 0.f) + b3q.y;
  float o2 = fmaf(a2, inv, 0.f) + b3q.z;
  float o3 = fmaf(a3, inv, 0.f) + b3q.w;
  o0 = o0 > 0.f ? o0 : expm1f(o0);
  o1 = o1 > 0.f ? o1 : expm1f(o1);
  o2 = o2 > 0.f ? o2 : expm1f(o2);
  o3 = o3 > 0.f ? o3 : expm1f(o3);
  if (sub == 0) *(float4*)&mrow[wl][c * 4] = make_float4(o0, o1, o2, o3);

  // in-wave MLP: lane j owns hidden unit j; col = lane>>5 (same-wave LDS RAW is in-order)
  float hid = b1v;
#pragma unroll
  for (int k = 0; k < 64; ++k)
    hid = fmaf(mrow[wl][k], w1s[k][j], hid);   // wave-uniform LDS broadcasts
  hid = fmaxf(hid, 0.f);
  float p = hid * w2v;
#pragma unroll
  for (int off = 1; off < 32; off <<= 1) p += __shfl_xor(p, off);
  if (j == 0) out[(size_t)wid * 2 + col] = p + b2v;
}

// ---------------- batch norm stats (deterministic partials, two dispatches) ----
__global__ __launch_bounds__(256) void bn_stats_kernel(const unsigned short* __restrict__ x, int N,
                                float* __restrict__ partials)   // [128][512]
{
  const int wid = threadIdx.x >> 6, lane = threadIdx.x & 63;
  const int gw = blockIdx.x * 4 + wid;
  const int tw = gridDim.x * 4;
  float4 s = make_float4(0.f, 0.f, 0.f, 0.f);
  float4 q = make_float4(0.f, 0.f, 0.f, 0.f);
#pragma unroll 4
  for (int r = gw; r < N; r += tw) {
    ushort4 u = ((const ushort4*)(x + (size_t)r * 256))[lane];
    float v0 = bf2f(u.x), v1 = bf2f(u.y), v2 = bf2f(u.z), v3 = bf2f(u.w);
    s.x += v0; s.y += v1; s.z += v2; s.w += v3;
    q.x = fmaf(v0, v0, q.x); q.y = fmaf(v1, v1, q.y);
    q.z = fmaf(v2, v2, q.z); q.w = fmaf(v3, v3, q.w);
  }
  __shared__ float ls[4][512];
  *(float4*)&ls[wid][lane * 4] = s;
  *(float4*)&ls[wid][256 + lane * 4] = q;
  __syncthreads();
  const int t = threadIdx.x;
  float a = ls[0][t] + ls[1][t] + ls[2][t] + ls[3][t];
  float b = ls[0][t + 256] + ls[1][t + 256] + ls[2][t + 256] + ls[3][t + 256];
  partials[blockIdx.x * 512 + t] = a;
  partials[blockIdx.x * 512 + 256 + t] = b;
}

__global__ void bn_final_kernel(const float* __restrict__ partials, int nblk,
                                const float* __restrict__ g, const float* __restrict__ be,
                                int N, float* __restrict__ scale, float* __restrict__ shift)
{
  int f = threadIdx.x;
  float s = 0.f, q = 0.f;
#pragma unroll 8
  for (int b = 0; b < nblk; ++b) {
    s += partials[b * 512 + f];
    q += partials[b * 512 + 256 + f];
  }
  float mu = s / N;
  float var = q / N - mu * mu;
  float rs = rsqrtf(var + 1e-5f);
  float sc = g[f] * rs;
  scale[f] = sc;
  shift[f] = be[f] - mu * sc;
}

// ---------------- host ----------------
extern "C" void kernel_launch(void* const* d_in, const int* in_sizes, int n_in,
                              void* d_out, int out_size, void* d_ws, size_t ws_size,
                              hipStream_t stream)
{
  const float* x   = (const float*)d_in[0];
  const int*   ei  = (const int*)d_in[1];
  const float* W1  = (const float*)d_in[2];
  const float* a1s = (const float*)d_in[3];
  const float* a1d = (const float*)d_in[4];
  const float* W2  = (const float*)d_in[6];
  const float* a2s = (const float*)d_in[7];
  const float* a2d = (const float*)d_in[8];
  const float* W3  = (const float*)d_in[10];
  const float* a3s = (const float*)d_in[11];
  const float* a3d = (const float*)d_in[12];
  const float* b3  = (const float*)d_in[13];
  const float* g1  = (const float*)d_in[14];
  const float* be1 = (const float*)d_in[15];
  const float* g2  = (const float*)d_in[16];
  const float* be2 = (const float*)d_in[17];
  const float* fw1 = (const float*)d_in[18];
  const float* fb1 = (const float*)d_in[19];
  const float* fw2 = (const float*)d_in[20];
  const float* fb2 = (const float*)d_in[21];
  float* out = (float*)d_out;

  const int F = 128;
  const int N = in_sizes[0] / F;
  const int E = in_sizes[1] / 2;
  const int Etot = E + N;
  const int* srcIdx = ei;
  const int* dstIdx = ei + E;

  char* w = (char*)d_ws;
  auto alloc = [&](size_t bytes) -> void* {
    void* p = (void*)w;
    w += (bytes + 255) & ~(size_t)255;
    return p;
  };
  unsigned short* h16  = (unsigned short*)alloc((size_t)N * 256 * 2);
  unsigned short* act16= (unsigned short*)alloc((size_t)N * 256 * 2);
  unsigned short* aBf  = (unsigned short*)alloc((size_t)N * 256 * 2);
  float* als     = (float*)alloc((size_t)N * 4 * 4);
  float* ald     = (float*)alloc((size_t)N * 4 * 4);
  const size_t cntPad = ((size_t)N * 4 + 255) & ~(size_t)255;
  int*   counts  = (int*)alloc((size_t)N * 4);
  int*   cursor  = (int*)alloc((size_t)N * 4);     // contiguous after counts
  int*   rowStart= (int*)alloc((size_t)(N + 1) * 4);
  int*   csrSrc  = (int*)alloc((size_t)Etot * 4);
  int*   bsums   = (int*)alloc((size_t)((N + 255) / 256) * 4);
  float* partials= (float*)alloc((size_t)128 * 512 * 4);
  float* scale1  = (float*)alloc(256 * 4);
  float* shift1  = (float*)alloc(256 * 4);
  float* scale2  = (float*)alloc(256 * 4);
  float* shift2  = (float*)alloc(256 * 4);
  unsigned short* w1h = (unsigned short*)alloc((size_t)128 * 256 * 2);
  unsigned short* w2h = (unsigned short*)alloc((size_t)256 * 256 * 2);
  unsigned short* w3h = (unsigned short*)alloc((size_t)256 * 64 * 2);
  (void)alloc(65536);   // slack for OOB staging reads of last GEMM block

  const int nb = (N + 255) / 256;
  const int ebk = (Etot + 255) / 256;
  const int aggBlocks = (N + 3) / 4;

  // ---- weight prep (one dispatch for all three) ----
  const int wtot = 128 * 256 + 256 * 256 + 256 * 64;
  wprep_all_kernel<<<(wtot + 255) / 256, 256, 0, stream>>>(W1, w1h, W2, w2h, W3, w3h);

  // ---- CSR build ----
  hipMemsetAsync(counts, 0, cntPad + (size_t)N * 4, stream);   // counts + cursor
  count_kernel<<<ebk, 256, 0, stream>>>(dstIdx, E, Etot, counts);
  block_sum_kernel<<<nb, 256, 0, stream>>>(counts, N, bsums);
  scan_bsums_kernel<<<1, 256, 0, stream>>>(bsums, nb);
  scan_write_kernel<<<nb, 256, 0, stream>>>(counts, N, bsums, rowStart, Etot);
  fill_kernel<<<ebk, 256, 0, stream>>>(srcIdx, dstIdx, E, Etot, rowStart, cursor, csrSrc);

  dim3 g12((N + 63) / 64, 2);      // layers 1,2: MI=4,WM=1,WN=2 -> BM=64,BN=128
  dim3 g3((N + 63) / 64, 1);       // layer 3:   MI=2,WM=2,WN=1 -> BM=64,BN=64

  // ---- GAT layer 1 ----
  split_kernel<<<2048, 256, 0, stream>>>(x, aBf, (size_t)N * 128 / 4);
  gemm_al<4, 1, 2, 2, 4><<<g12, 128, 0, stream>>>(aBf, w1h, a1s, a1d, h16, als, ald, N);
  aggregate_fused4<<<aggBlocks, 256, 0, stream>>>(h16, als, ald, csrSrc, rowStart, act16, N);
  bn_stats_kernel<<<128, 256, 0, stream>>>(act16, N, partials);
  bn_final_kernel<<<1, 256, 0, stream>>>(partials, 128, g1, be1, N, scale1, shift1);

  // ---- GAT layer 2 ----
  bnsplit_kernel<<<2048, 256, 0, stream>>>(act16, scale1, shift1, aBf, (size_t)N * 64);
  gemm_al<4, 1, 2, 4, 4><<<g12, 128, 0, stream>>>(aBf, w2h, a2s, a2d, h16, als, ald, N);
  aggregate_fused4<<<aggBlocks, 256, 0, stream>>>(h16, als, ald, csrSrc, rowStart, act16, N);
  bn_stats_kernel<<<128, 256, 0, stream>>>(act16, N, partials);
  bn_final_kernel<<<1, 256, 0, stream>>>(partials, 128, g2, be2, N, scale2, shift2);

  // ---- GAT layer 3 + fused MLP head ----
  bnsplit_kernel<<<2048, 256, 0, stream>>>(act16, scale2, shift2, aBf, (size_t)N * 64);
  gemm_al<2, 2, 1, 4, 1><<<g3, 128, 0, stream>>>(aBf, w3h, a3s, a3d, h16, als, ald, N);
  agg3_mlp_kernel<<<aggBlocks, 256, 0, stream>>>(h16, als, ald, csrSrc, rowStart,
                                                 b3, fw1, fb1, fw2, fb2, out, N);
}

// Round 18
// 309.071 us; speedup vs baseline: 1.0099x; 1.0025x over previous
//
#include <hip/hip_runtime.h>
#include <math.h>
#include <stdint.h>

typedef __attribute__((ext_vector_type(8))) short short8v;
typedef __attribute__((ext_vector_type(4))) float float4v;

__device__ __forceinline__ float bf2f(unsigned short u) {
  return __uint_as_float((unsigned int)u << 16);
}
__device__ __forceinline__ unsigned short f2bf(float f) {   // RNE
  unsigned int u = __float_as_uint(f);
  unsigned int r = (u + 0x7FFFu + ((u >> 16) & 1u)) >> 16;
  return (unsigned short)r;
}
__device__ __forceinline__ float exp_lrelu(float x) {
  x = x > 0.f ? x : 0.2f * x;
  return expf(x);       // softmax shift-invariant: segment-max skipped
}

typedef __attribute__((address_space(3))) void lds_void;
typedef const __attribute__((address_space(1))) void glb_void;
__device__ __forceinline__ void gload_lds16(const void* g, void* l) {
  __builtin_amdgcn_global_load_lds((glb_void*)g, (lds_void*)l, 16, 0, 0);
}

// ---------------- weight prep (all 3 weights in one dispatch) ----------------
__device__ __forceinline__ void wprep_one(const float* W, unsigned short* Wh,
                                          int t, int K, int Nw)
{
  int i = t & 7;
  int lane = (t >> 3) & 63;
  int frag = t >> 9;
  int ktiles = K >> 5;
  int n_tile = frag / ktiles, k_tile = frag - n_tile * ktiles;
  int k = k_tile * 32 + ((lane >> 4) << 3) + i;
  int n = (n_tile << 4) + (lane & 15);
  Wh[t] = f2bf(W[(size_t)k * Nw + n]);
}

__global__ void wprep_all_kernel(const float* __restrict__ W1, unsigned short* __restrict__ w1h,
                                 const float* __restrict__ W2, unsigned short* __restrict__ w2h,
                                 const float* __restrict__ W3, unsigned short* __restrict__ w3h)
{
  int t = blockIdx.x * 256 + threadIdx.x;
  const int s1 = 128 * 256, s2 = 256 * 256, s3 = 256 * 64;
  if (t < s1) { wprep_one(W1, w1h, t, 128, 256); return; }
  t -= s1;
  if (t < s2) { wprep_one(W2, w2h, t, 256, 256); return; }
  t -= s2;
  if (t < s3) { wprep_one(W3, w3h, t, 256, 64); }
}

// ---------------- A-side: x fp32 -> bf16 (RNE) ----------------
__global__ __launch_bounds__(256) void split_kernel(const float* __restrict__ in,
    unsigned short* __restrict__ hi, size_t n4)
{
  size_t i0 = (size_t)blockIdx.x * 256 + threadIdx.x;
  size_t stride = (size_t)gridDim.x * 256;
  for (size_t idx = i0; idx < n4; idx += stride) {
    float4 v = ((const float4*)in)[idx];
    ushort4 h;
    h.x = f2bf(v.x); h.y = f2bf(v.y); h.z = f2bf(v.z); h.w = f2bf(v.w);
    ((ushort4*)hi)[idx] = h;
  }
}

// BN + ELU -> bf16 (RNE), reading bf16 act
__global__ __launch_bounds__(256) void bnsplit_kernel(const unsigned short* __restrict__ act,
    const float* __restrict__ scale, const float* __restrict__ shift,
    unsigned short* __restrict__ hi, size_t nchunks)
{
  size_t i0 = (size_t)blockIdx.x * 256 + threadIdx.x;
  size_t stride = (size_t)gridDim.x * 256;
  for (size_t idx = i0; idx < nchunks; idx += stride) {
    ushort4 u = ((const ushort4*)act)[idx];
    int f = (int)((idx * 4) & 255);
    float4 sc = *(const float4*)(scale + f);
    float4 sh = *(const float4*)(shift + f);
    float v0 = fmaf(bf2f(u.x), sc.x, sh.x);
    float v1 = fmaf(bf2f(u.y), sc.y, sh.y);
    float v2 = fmaf(bf2f(u.z), sc.z, sh.z);
    float v3 = fmaf(bf2f(u.w), sc.w, sh.w);
    v0 = v0 > 0.f ? v0 : expm1f(v0);
    v1 = v1 > 0.f ? v1 : expm1f(v1);
    v2 = v2 > 0.f ? v2 : expm1f(v2);
    v3 = v3 > 0.f ? v3 : expm1f(v3);
    ushort4 h;
    h.x = f2bf(v0); h.y = f2bf(v1); h.z = f2bf(v2); h.w = f2bf(v3);
    ((ushort4*)hi)[idx] = h;
  }
}

// ---------------- single-bf16 MFMA GEMM + fused al epilogue, LDS-staged A ----------------
template<int MI, int WM, int WN, int KSTEPS, int HEADS>
__global__ __launch_bounds__(128) void gemm_al(
    const unsigned short* __restrict__ Ah, const unsigned short* __restrict__ Bh,
    const float* __restrict__ a_s, const float* __restrict__ a_d,
    unsigned short* __restrict__ C, float* __restrict__ al_s, float* __restrict__ al_d,
    int M)
{
  constexpr int NWAVES = WM * WN;            // 2
  constexpr int BM = WM * MI * 16;           // 64
  constexpr int TILEB = BM * 64 * 2;         // 8 KB per buffer
  constexpr int Nw = HEADS * 64;
  constexpr int K = KSTEPS * 64;
  constexpr int KT32 = KSTEPS * 2;
  __shared__ __align__(16) unsigned char smem[2][TILEB];

  const int wid = threadIdx.x >> 6, lane = threadIdx.x & 63;
  const int wm = wid / WN, wn = wid % WN;
  const int gn = blockIdx.y * WN + wn;       // global 64-col tile index
  const int m0 = blockIdx.x * BM;
  const int n0 = gn * 64;
  const int ar = lane & 15;
  const int cchunk = lane >> 4;
  const int ntile0 = n0 >> 4;

  float4v acc[MI][4];
#pragma unroll
  for (int mi = 0; mi < MI; ++mi)
#pragma unroll
    for (int ni = 0; ni < 4; ++ni)
      acc[mi][ni] = (float4v){0.f, 0.f, 0.f, 0.f};

  auto stage = [&](int buf, int ks) {
#pragma unroll
    for (int c = wid; c < 8; c += NWAVES) {
      const unsigned short* gp = Ah + (size_t)(m0 + lane) * K + ks * 64 + c * 8;
      gload_lds16(gp, &smem[buf][c * 1024 + lane * 16]);
    }
  };

  stage(0, 0);
  int cur = 0;
  for (int ks = 0; ks < KSTEPS; ++ks) {
    __syncthreads();   // stage(cur) complete; buffers handed off
    short8v bh[2][4];
#pragma unroll
    for (int hh = 0; hh < 2; ++hh)
#pragma unroll
      for (int ni = 0; ni < 4; ++ni) {
        int kt = ks * 2 + hh;
        size_t off = (((size_t)(ntile0 + ni) * KT32 + kt) * 64 + lane) * 8;
        bh[hh][ni] = *(const short8v*)(Bh + off);
      }
    if (ks + 1 < KSTEPS) stage(cur ^ 1, ks + 1);
    short8v ah[2][MI];
#pragma unroll
    for (int hh = 0; hh < 2; ++hh)
#pragma unroll
      for (int mi = 0; mi < MI; ++mi) {
        int row = wm * MI * 16 + mi * 16 + ar;
        int c = hh * 4 + cchunk;
        ah[hh][mi] = *(const short8v*)&smem[cur][c * 1024 + row * 16];
      }
#pragma unroll
    for (int hh = 0; hh < 2; ++hh)
#pragma unroll
      for (int mi = 0; mi < MI; ++mi)
#pragma unroll
        for (int ni = 0; ni < 4; ++ni)
          acc[mi][ni] = __builtin_amdgcn_mfma_f32_16x16x32_bf16(ah[hh][mi], bh[hh][ni], acc[mi][ni], 0, 0, 0);
    cur ^= 1;
  }

  const int cc = lane & 15;
#pragma unroll
  for (int mi = 0; mi < MI; ++mi) {
    int rowb = m0 + wm * MI * 16 + mi * 16 + ((lane >> 4) << 2);
#pragma unroll
    for (int r = 0; r < 4; ++r) {
      int row = rowb + r;
      if (row < M) {
#pragma unroll
        for (int ni = 0; ni < 4; ++ni)
          C[(size_t)row * Nw + n0 + ni * 16 + cc] = f2bf(acc[mi][ni][r]);
      }
    }
  }

  // fused attention-logit epilogue (bf16-rounded h = downstream values)
  const int head = (HEADS == 4) ? gn : 0;
  float as_[4], ad_[4];
#pragma unroll
  for (int ni = 0; ni < 4; ++ni) {
    as_[ni] = a_s[head * 64 + ni * 16 + cc];
    ad_[ni] = a_d[head * 64 + ni * 16 + cc];
  }
#pragma unroll
  for (int mi = 0; mi < MI; ++mi) {
#pragma unroll
    for (int r = 0; r < 4; ++r) {
      float h0 = bf2f(f2bf(acc[mi][0][r]));
      float h1 = bf2f(f2bf(acc[mi][1][r]));
      float h2 = bf2f(f2bf(acc[mi][2][r]));
      float h3 = bf2f(f2bf(acc[mi][3][r]));
      float ps = h0 * as_[0] + h1 * as_[1] + h2 * as_[2] + h3 * as_[3];
      float pd = h0 * ad_[0] + h1 * ad_[1] + h2 * ad_[2] + h3 * ad_[3];
#pragma unroll
      for (int off = 1; off < 16; off <<= 1) {
        ps += __shfl_xor(ps, off);
        pd += __shfl_xor(pd, off);
      }
      int row = m0 + wm * MI * 16 + mi * 16 + ((lane >> 4) << 2) + r;
      if (cc == 0 && row < M) {
        al_s[row * HEADS + head] = ps;
        al_d[row * HEADS + head] = pd;
      }
    }
  }
}

// ---------------- CSR build ----------------
__global__ void count_kernel(const int* __restrict__ dst, int E, int Etot, int* __restrict__ counts)
{
  int e = blockIdx.x * 256 + threadIdx.x;
  if (e >= Etot) return;
  int d = (e < E) ? dst[e] : (e - E);
  atomicAdd(&counts[d], 1);
}

__global__ void block_sum_kernel(const int* __restrict__ counts, int N, int* __restrict__ bsums)
{
  __shared__ int sd[256];
  int i = blockIdx.x * 256 + threadIdx.x;
  sd[threadIdx.x] = (i < N) ? counts[i] : 0;
  __syncthreads();
  for (int off = 128; off; off >>= 1) {
    if (threadIdx.x < off) sd[threadIdx.x] += sd[threadIdx.x + off];
    __syncthreads();
  }
  if (threadIdx.x == 0) bsums[blockIdx.x] = sd[0];
}

__global__ void scan_bsums_kernel(int* bsums, int nb)
{
  __shared__ int sd[256];
  int t = threadIdx.x;
  int v = (t < nb) ? bsums[t] : 0;
  sd[t] = v;
  __syncthreads();
  for (int off = 1; off < 256; off <<= 1) {
    int x = (t >= off) ? sd[t - off] : 0;
    __syncthreads();
    sd[t] += x;
    __syncthreads();
  }
  if (t < nb) bsums[t] = sd[t] - v;  // exclusive
}

__global__ void scan_write_kernel(const int* __restrict__ counts, int N,
                                  const int* __restrict__ bsums, int* __restrict__ rowStart, int Etot)
{
  __shared__ int sd[256];
  int i = blockIdx.x * 256 + threadIdx.x;
  int v = (i < N) ? counts[i] : 0;
  sd[threadIdx.x] = v;
  __syncthreads();
  for (int off = 1; off < 256; off <<= 1) {
    int x = (threadIdx.x >= off) ? sd[threadIdx.x - off] : 0;
    __syncthreads();
    sd[threadIdx.x] += x;
    __syncthreads();
  }
  if (i < N) rowStart[i] = bsums[blockIdx.x] + sd[threadIdx.x] - v;  // exclusive
  if (i == N - 1) rowStart[N] = Etot;
}

__global__ void fill_kernel(const int* __restrict__ src, const int* __restrict__ dst,
                            int E, int Etot, const int* __restrict__ rowStart,
                            int* __restrict__ cursor, int* __restrict__ csrSrc)
{
  int e = blockIdx.x * 256 + threadIdx.x;
  if (e >= Etot) return;
  int s, d;
  if (e < E) { s = src[e]; d = dst[e]; } else { s = d = e - E; }
  int pos = rowStart[d] + atomicAdd(&cursor[d], 1);
  csrSrc[pos] = s;
}

// ---------------- fused aggregation, 4-head layers (bf16 out) ----------------
// 2 edges per memory instruction: lane = 32*sub + c; lane reads 16B (8 feats) of edge i+sub.
__global__ __launch_bounds__(256) void aggregate_fused4(
    const unsigned short* __restrict__ h16,
    const float* __restrict__ als, const float* __restrict__ ald,
    const int* __restrict__ csrSrc, const int* __restrict__ rowStart,
    unsigned short* __restrict__ outp, int N)
{
  __shared__ float ldsW[4][256];
  const int wl = threadIdx.x >> 6;
  int wid = blockIdx.x * 4 + wl;
  if (wid >= N) return;
  const int lane = threadIdx.x & 63;
  const int sub = lane >> 5, c = lane & 31;   // feature slice c*8..c*8+7
  const int head = c >> 3;
  const int start = rowStart[wid], end = rowStart[wid + 1];

  float4 adv = ((const float4*)ald)[wid];
  float acc[8] = {};
  float wsum = 0.f;

  for (int base = start; base < end; base += 64) {
    int cnt = end - base; if (cnt > 64) cnt = 64;
    int s_l = 0;
    if (lane < cnt) {
      s_l = csrSrc[base + lane];
      float4 av = ((const float4*)als)[s_l];
      float4 w4;
      w4.x = exp_lrelu(av.x + adv.x);
      w4.y = exp_lrelu(av.y + adv.y);
      w4.z = exp_lrelu(av.z + adv.z);
      w4.w = exp_lrelu(av.w + adv.w);
      *(float4*)&ldsW[wl][lane * 4] = w4;
    }
    for (int i = 0; i < cnt; i += 2) {
      int e = i + sub;                         // <= 63
      int s = __shfl(s_l, e);                  // s_l==0 for lanes>=cnt -> safe row 0
      float w = (e < cnt) ? ldsW[wl][e * 4 + head] : 0.f;
      short8v r = *(const short8v*)(h16 + (size_t)s * 256 + c * 8);
      wsum += w;
#pragma unroll
      for (int q = 0; q < 8; ++q)
        acc[q] = fmaf(w, bf2f((unsigned short)r[q]), acc[q]);
    }
  }
  // merge the two sub-groups (partner lane has same c)
#pragma unroll
  for (int q = 0; q < 8; ++q) acc[q] += __shfl_xor(acc[q], 32);
  wsum += __shfl_xor(wsum, 32);

  if (sub == 0) {
    float inv = 1.0f / wsum;
    short8v o;
#pragma unroll
    for (int q = 0; q < 8; ++q) o[q] = (short)f2bf(acc[q] * inv);
    *(short8v*)(outp + (size_t)wid * 256 + c * 8) = o;
  }
}

// ---------------- layer-3 aggregation + bias + ELU (fp32 out) ----------------
// 4 edges per memory instruction: lane = 16*sub + c; lane reads 8B (4 feats) of edge i+sub.
__global__ __launch_bounds__(256) void aggregate3_kernel(
    const unsigned short* __restrict__ h16,
    const float* __restrict__ als, const float* __restrict__ ald,
    const int* __restrict__ csrSrc, const int* __restrict__ rowStart,
    const float* __restrict__ b3, float* __restrict__ outp, int N)
{
  __shared__ float ldsW[4][64];
  const int t = threadIdx.x;
  const int wl = t >> 6, lane = t & 63;
  const int sub = lane >> 4, c = lane & 15;   // feature slice c*4..c*4+3
  int wid = blockIdx.x * 4 + wl;
  if (wid >= N) return;
  const int start = rowStart[wid], end = rowStart[wid + 1];
  const float ad0 = ald[wid];
  const float4 b3q = ((const float4*)b3)[c];

  float a0 = 0.f, a1 = 0.f, a2 = 0.f, a3 = 0.f, wsum = 0.f;
  for (int base = start; base < end; base += 64) {
    int cnt = end - base; if (cnt > 64) cnt = 64;
    int s_l = 0;
    if (lane < cnt) {
      s_l = csrSrc[base + lane];
      ldsW[wl][lane] = exp_lrelu(als[s_l] + ad0);
    }
    for (int i = 0; i < cnt; i += 4) {
      int e = i + sub;                         // <= 63
      int s = __shfl(s_l, e);                  // safe: 0 for invalid
      float w = (e < cnt) ? ldsW[wl][e] : 0.f;
      ushort4 r = ((const ushort4*)(h16 + (size_t)s * 64))[c];
      wsum += w;
      a0 = fmaf(w, bf2f(r.x), a0);
      a1 = fmaf(w, bf2f(r.y), a1);
      a2 = fmaf(w, bf2f(r.z), a2);
      a3 = fmaf(w, bf2f(r.w), a3);
    }
  }
  // merge the four sub-groups (partner lanes share c)
  a0 += __shfl_xor(a0, 16); a1 += __shfl_xor(a1, 16);
  a2 += __shfl_xor(a2, 16); a3 += __shfl_xor(a3, 16);
  wsum += __shfl_xor(wsum, 16);
  a0 += __shfl_xor(a0, 32); a1 += __shfl_xor(a1, 32);
  a2 += __shfl_xor(a2, 32); a3 += __shfl_xor(a3, 32);
  wsum += __shfl_xor(wsum, 32);

  if (sub == 0) {
    float inv = 1.0f / wsum;
    float o0 = a0 * inv + b3q.x;
    float o1 = a1 * inv + b3q.y;
    float o2 = a2 * inv + b3q.z;
    float o3 = a3 * inv + b3q.w;
    o0 = o0 > 0.f ? o0 : expm1f(o0);
    o1 = o1 > 0.f ? o1 : expm1f(o1);
    o2 = o2 > 0.f ? o2 : expm1f(o2);
    o3 = o3 > 0.f ? o3 : expm1f(o3);
    *(float4*)(outp + (size_t)wid * 64 + c * 4) = make_float4(o0, o1, o2, o3);
  }
}

// ---------------- MLP head: thread-per-node, LDS weight broadcast ----------------
// Wave-uniform w1s reads amortize each ds_read across 64 nodes (one per lane).
__global__ __launch_bounds__(256) void mlp_kernel(const float* __restrict__ h,
                           const float* __restrict__ fw1,
                           const float* __restrict__ fb1, const float* __restrict__ fw2,
                           const float* __restrict__ fb2, float* __restrict__ out, int N)
{
  __shared__ float w1s[64][32];
  __shared__ float w2s[32][2];
  __shared__ float b1s[32];
  const int t = threadIdx.x;
  for (int i = t; i < 64 * 32; i += 256) w1s[i >> 5][i & 31] = fw1[i];
  if (t < 64) w2s[t >> 1][t & 1] = fw2[t];
  if (t < 32) b1s[t] = fb1[t];
  __syncthreads();

  int n = blockIdx.x * 256 + t;
  if (n >= N) return;

  float hv[64];
#pragma unroll
  for (int k4 = 0; k4 < 16; ++k4) {
    float4 v = *(const float4*)(h + (size_t)n * 64 + k4 * 4);
    hv[k4 * 4 + 0] = v.x; hv[k4 * 4 + 1] = v.y;
    hv[k4 * 4 + 2] = v.z; hv[k4 * 4 + 3] = v.w;
  }
  float hid[32];
#pragma unroll
  for (int j = 0; j < 32; ++j) hid[j] = b1s[j];
#pragma unroll
  for (int k = 0; k < 64; ++k) {
    float hk = hv[k];
#pragma unroll
    for (int jb = 0; jb < 8; ++jb) {
      float4 wv = *(const float4*)&w1s[k][jb * 4];
      hid[jb * 4 + 0] = fmaf(hk, wv.x, hid[jb * 4 + 0]);
      hid[jb * 4 + 1] = fmaf(hk, wv.y, hid[jb * 4 + 1]);
      hid[jb * 4 + 2] = fmaf(hk, wv.z, hid[jb * 4 + 2]);
      hid[jb * 4 + 3] = fmaf(hk, wv.w, hid[jb * 4 + 3]);
    }
  }
  float p0 = fb2[0], p1 = fb2[1];
#pragma unroll
  for (int j = 0; j < 32; ++j) {
    float r = fmaxf(hid[j], 0.f);
    p0 = fmaf(r, w2s[j][0], p0);
    p1 = fmaf(r, w2s[j][1], p1);
  }
  *(float2*)(out + (size_t)n * 2) = make_float2(p0, p1);
}

// ---------------- batch norm stats (deterministic partials, two dispatches) ----
__global__ __launch_bounds__(256) void bn_stats_kernel(const unsigned short* __restrict__ x, int N,
                                float* __restrict__ partials)   // [128][512]
{
  const int wid = threadIdx.x >> 6, lane = threadIdx.x & 63;
  const int gw = blockIdx.x * 4 + wid;
  const int tw = gridDim.x * 4;
  float4 s = make_float4(0.f, 0.f, 0.f, 0.f);
  float4 q = make_float4(0.f, 0.f, 0.f, 0.f);
#pragma unroll 4
  for (int r = gw; r < N; r += tw) {
    ushort4 u = ((const ushort4*)(x + (size_t)r * 256))[lane];
    float v0 = bf2f(u.x), v1 = bf2f(u.y), v2 = bf2f(u.z), v3 = bf2f(u.w);
    s.x += v0; s.y += v1; s.z += v2; s.w += v3;
    q.x = fmaf(v0, v0, q.x); q.y = fmaf(v1, v1, q.y);
    q.z = fmaf(v2, v2, q.z); q.w = fmaf(v3, v3, q.w);
  }
  __shared__ float ls[4][512];
  *(float4*)&ls[wid][lane * 4] = s;
  *(float4*)&ls[wid][256 + lane * 4] = q;
  __syncthreads();
  const int t = threadIdx.x;
  float a = ls[0][t] + ls[1][t] + ls[2][t] + ls[3][t];
  float b = ls[0][t + 256] + ls[1][t + 256] + ls[2][t + 256] + ls[3][t + 256];
  partials[blockIdx.x * 512 + t] = a;
  partials[blockIdx.x * 512 + 256 + t] = b;
}

__global__ void bn_final_kernel(const float* __restrict__ partials, int nblk,
                                const float* __restrict__ g, const float* __restrict__ be,
                                int N, float* __restrict__ scale, float* __restrict__ shift)
{
  int f = threadIdx.x;
  float s = 0.f, q = 0.f;
#pragma unroll 8
  for (int b = 0; b < nblk; ++b) {
    s += partials[b * 512 + f];
    q += partials[b * 512 + 256 + f];
  }
  float mu = s / N;
  float var = q / N - mu * mu;
  float rs = rsqrtf(var + 1e-5f);
  float sc = g[f] * rs;
  scale[f] = sc;
  shift[f] = be[f] - mu * sc;
}

// ---------------- host ----------------
extern "C" void kernel_launch(void* const* d_in, const int* in_sizes, int n_in,
                              void* d_out, int out_size, void* d_ws, size_t ws_size,
                              hipStream_t stream)
{
  const float* x   = (const float*)d_in[0];
  const int*   ei  = (const int*)d_in[1];
  const float* W1  = (const float*)d_in[2];
  const float* a1s = (const float*)d_in[3];
  const float* a1d = (const float*)d_in[4];
  const float* W2  = (const float*)d_in[6];
  const float* a2s = (const float*)d_in[7];
  const float* a2d = (const float*)d_in[8];
  const float* W3  = (const float*)d_in[10];
  const float* a3s = (const float*)d_in[11];
  const float* a3d = (const float*)d_in[12];
  const float* b3  = (const float*)d_in[13];
  const float* g1  = (const float*)d_in[14];
  const float* be1 = (const float*)d_in[15];
  const float* g2  = (const float*)d_in[16];
  const float* be2 = (const float*)d_in[17];
  const float* fw1 = (const float*)d_in[18];
  const float* fb1 = (const float*)d_in[19];
  const float* fw2 = (const float*)d_in[20];
  const float* fb2 = (const float*)d_in[21];
  float* out = (float*)d_out;

  const int F = 128;
  const int N = in_sizes[0] / F;
  const int E = in_sizes[1] / 2;
  const int Etot = E + N;
  const int* srcIdx = ei;
  const int* dstIdx = ei + E;

  char* w = (char*)d_ws;
  auto alloc = [&](size_t bytes) -> void* {
    void* p = (void*)w;
    w += (bytes + 255) & ~(size_t)255;
    return p;
  };
  unsigned short* h16  = (unsigned short*)alloc((size_t)N * 256 * 2);
  unsigned short* act16= (unsigned short*)alloc((size_t)N * 256 * 2);
  unsigned short* aBf  = (unsigned short*)alloc((size_t)N * 256 * 2);
  float* actf    = (float*)alloc((size_t)N * 64 * 4);
  float* als     = (float*)alloc((size_t)N * 4 * 4);
  float* ald     = (float*)alloc((size_t)N * 4 * 4);
  const size_t cntPad = ((size_t)N * 4 + 255) & ~(size_t)255;
  int*   counts  = (int*)alloc((size_t)N * 4);
  int*   cursor  = (int*)alloc((size_t)N * 4);     // contiguous after counts
  int*   rowStart= (int*)alloc((size_t)(N + 1) * 4);
  int*   csrSrc  = (int*)alloc((size_t)Etot * 4);
  int*   bsums   = (int*)alloc((size_t)((N + 255) / 256) * 4);
  float* partials= (float*)alloc((size_t)128 * 512 * 4);
  float* scale1  = (float*)alloc(256 * 4);
  float* shift1  = (float*)alloc(256 * 4);
  float* scale2  = (float*)alloc(256 * 4);
  float* shift2  = (float*)alloc(256 * 4);
  unsigned short* w1h = (unsigned short*)alloc((size_t)128 * 256 * 2);
  unsigned short* w2h = (unsigned short*)alloc((size_t)256 * 256 * 2);
  unsigned short* w3h = (unsigned short*)alloc((size_t)256 * 64 * 2);
  (void)alloc(65536);   // slack for OOB staging reads of last GEMM block

  const int nb = (N + 255) / 256;
  const int ebk = (Etot + 255) / 256;
  const int aggBlocks = (N + 3) / 4;

  // ---- weight prep (one dispatch for all three) ----
  const int wtot = 128 * 256 + 256 * 256 + 256 * 64;
  wprep_all_kernel<<<(wtot + 255) / 256, 256, 0, stream>>>(W1, w1h, W2, w2h, W3, w3h);

  // ---- CSR build ----
  hipMemsetAsync(counts, 0, cntPad + (size_t)N * 4, stream);   // counts + cursor
  count_kernel<<<ebk, 256, 0, stream>>>(dstIdx, E, Etot, counts);
  block_sum_kernel<<<nb, 256, 0, stream>>>(counts, N, bsums);
  scan_bsums_kernel<<<1, 256, 0, stream>>>(bsums, nb);
  scan_write_kernel<<<nb, 256, 0, stream>>>(counts, N, bsums, rowStart, Etot);
  fill_kernel<<<ebk, 256, 0, stream>>>(srcIdx, dstIdx, E, Etot, rowStart, cursor, csrSrc);

  dim3 g12((N + 63) / 64, 2);      // layers 1,2: MI=4,WM=1,WN=2 -> BM=64,BN=128
  dim3 g3((N + 63) / 64, 1);       // layer 3:   MI=2,WM=2,WN=1 -> BM=64,BN=64

  // ---- GAT layer 1 ----
  split_kernel<<<2048, 256, 0, stream>>>(x, aBf, (size_t)N * 128 / 4);
  gemm_al<4, 1, 2, 2, 4><<<g12, 128, 0, stream>>>(aBf, w1h, a1s, a1d, h16, als, ald, N);
  aggregate_fused4<<<aggBlocks, 256, 0, stream>>>(h16, als, ald, csrSrc, rowStart, act16, N);
  bn_stats_kernel<<<128, 256, 0, stream>>>(act16, N, partials);
  bn_final_kernel<<<1, 256, 0, stream>>>(partials, 128, g1, be1, N, scale1, shift1);

  // ---- GAT layer 2 ----
  bnsplit_kernel<<<2048, 256, 0, stream>>>(act16, scale1, shift1, aBf, (size_t)N * 64);
  gemm_al<4, 1, 2, 4, 4><<<g12, 128, 0, stream>>>(aBf, w2h, a2s, a2d, h16, als, ald, N);
  aggregate_fused4<<<aggBlocks, 256, 0, stream>>>(h16, als, ald, csrSrc, rowStart, act16, N);
  bn_stats_kernel<<<128, 256, 0, stream>>>(act16, N, partials);
  bn_final_kernel<<<1, 256, 0, stream>>>(partials, 128, g2, be2, N, scale2, shift2);

  // ---- GAT layer 3 ----
  bnsplit_kernel<<<2048, 256, 0, stream>>>(act16, scale2, shift2, aBf, (size_t)N * 64);
  gemm_al<2, 2, 1, 4, 1><<<g3, 128, 0, stream>>>(aBf, w3h, a3s, a3d, h16, als, ald, N);
  aggregate3_kernel<<<aggBlocks, 256, 0, stream>>>(h16, als, ald, csrSrc, rowStart, b3, actf, N);

  // ---- MLP head ----
  mlp_kernel<<<(N + 255) / 256, 256, 0, stream>>>(actf, fw1, fb1, fw2, fb2, out, N);
}

// Round 19
// 297.754 us; speedup vs baseline: 1.0482x; 1.0380x over previous
//
#include <hip/hip_runtime.h>
#include <math.h>
#include <stdint.h>

typedef __attribute__((ext_vector_type(8))) short short8v;
typedef __attribute__((ext_vector_type(4))) float float4v;

__device__ __forceinline__ float bf2f(unsigned short u) {
  return __uint_as_float((unsigned int)u << 16);
}
__device__ __forceinline__ unsigned short f2bf(float f) {   // RNE
  unsigned int u = __float_as_uint(f);
  unsigned int r = (u + 0x7FFFu + ((u >> 16) & 1u)) >> 16;
  return (unsigned short)r;
}
__device__ __forceinline__ float exp_lrelu(float x) {
  x = x > 0.f ? x : 0.2f * x;
  return __expf(x);     // fast exp (v_exp_f32); softmax shift-invariant: max skipped
}
__device__ __forceinline__ float elu_fast(float x) {
  return x > 0.f ? x : __expf(x) - 1.f;
}

typedef __attribute__((address_space(3))) void lds_void;
typedef const __attribute__((address_space(1))) void glb_void;
__device__ __forceinline__ void gload_lds16(const void* g, void* l) {
  __builtin_amdgcn_global_load_lds((glb_void*)g, (lds_void*)l, 16, 0, 0);
}

// ---------------- weight prep (all 3 weights in one dispatch) ----------------
__device__ __forceinline__ void wprep_one(const float* W, unsigned short* Wh,
                                          int t, int K, int Nw)
{
  int i = t & 7;
  int lane = (t >> 3) & 63;
  int frag = t >> 9;
  int ktiles = K >> 5;
  int n_tile = frag / ktiles, k_tile = frag - n_tile * ktiles;
  int k = k_tile * 32 + ((lane >> 4) << 3) + i;
  int n = (n_tile << 4) + (lane & 15);
  Wh[t] = f2bf(W[(size_t)k * Nw + n]);
}

__global__ void wprep_all_kernel(const float* __restrict__ W1, unsigned short* __restrict__ w1h,
                                 const float* __restrict__ W2, unsigned short* __restrict__ w2h,
                                 const float* __restrict__ W3, unsigned short* __restrict__ w3h)
{
  int t = blockIdx.x * 256 + threadIdx.x;
  const int s1 = 128 * 256, s2 = 256 * 256, s3 = 256 * 64;
  if (t < s1) { wprep_one(W1, w1h, t, 128, 256); return; }
  t -= s1;
  if (t < s2) { wprep_one(W2, w2h, t, 256, 256); return; }
  t -= s2;
  if (t < s3) { wprep_one(W3, w3h, t, 256, 64); }
}

// ---------------- A-side: x fp32 -> bf16 (RNE) ----------------
__global__ __launch_bounds__(256) void split_kernel(const float* __restrict__ in,
    unsigned short* __restrict__ hi, size_t n4)
{
  size_t i0 = (size_t)blockIdx.x * 256 + threadIdx.x;
  size_t stride = (size_t)gridDim.x * 256;
  for (size_t idx = i0; idx < n4; idx += stride) {
    float4 v = ((const float4*)in)[idx];
    ushort4 h;
    h.x = f2bf(v.x); h.y = f2bf(v.y); h.z = f2bf(v.z); h.w = f2bf(v.w);
    ((ushort4*)hi)[idx] = h;
  }
}

// BN + ELU -> bf16 (RNE), reading bf16 act
__global__ __launch_bounds__(256) void bnsplit_kernel(const unsigned short* __restrict__ act,
    const float* __restrict__ scale, const float* __restrict__ shift,
    unsigned short* __restrict__ hi, size_t nchunks)
{
  size_t i0 = (size_t)blockIdx.x * 256 + threadIdx.x;
  size_t stride = (size_t)gridDim.x * 256;
  for (size_t idx = i0; idx < nchunks; idx += stride) {
    ushort4 u = ((const ushort4*)act)[idx];
    int f = (int)((idx * 4) & 255);
    float4 sc = *(const float4*)(scale + f);
    float4 sh = *(const float4*)(shift + f);
    float v0 = elu_fast(fmaf(bf2f(u.x), sc.x, sh.x));
    float v1 = elu_fast(fmaf(bf2f(u.y), sc.y, sh.y));
    float v2 = elu_fast(fmaf(bf2f(u.z), sc.z, sh.z));
    float v3 = elu_fast(fmaf(bf2f(u.w), sc.w, sh.w));
    ushort4 h;
    h.x = f2bf(v0); h.y = f2bf(v1); h.z = f2bf(v2); h.w = f2bf(v3);
    ((ushort4*)hi)[idx] = h;
  }
}

// ---------------- single-bf16 MFMA GEMM + fused al epilogue, LDS-staged A ----------------
template<int MI, int WM, int WN, int KSTEPS, int HEADS>
__global__ __launch_bounds__(128) void gemm_al(
    const unsigned short* __restrict__ Ah, const unsigned short* __restrict__ Bh,
    const float* __restrict__ a_s, const float* __restrict__ a_d,
    unsigned short* __restrict__ C, float* __restrict__ al_s, float* __restrict__ al_d,
    int M)
{
  constexpr int NWAVES = WM * WN;            // 2
  constexpr int BM = WM * MI * 16;           // 64
  constexpr int TILEB = BM * 64 * 2;         // 8 KB per buffer
  constexpr int Nw = HEADS * 64;
  constexpr int K = KSTEPS * 64;
  constexpr int KT32 = KSTEPS * 2;
  __shared__ __align__(16) unsigned char smem[2][TILEB];

  const int wid = threadIdx.x >> 6, lane = threadIdx.x & 63;
  const int wm = wid / WN, wn = wid % WN;
  const int gn = blockIdx.y * WN + wn;       // global 64-col tile index
  const int m0 = blockIdx.x * BM;
  const int n0 = gn * 64;
  const int ar = lane & 15;
  const int cchunk = lane >> 4;
  const int ntile0 = n0 >> 4;

  float4v acc[MI][4];
#pragma unroll
  for (int mi = 0; mi < MI; ++mi)
#pragma unroll
    for (int ni = 0; ni < 4; ++ni)
      acc[mi][ni] = (float4v){0.f, 0.f, 0.f, 0.f};

  auto stage = [&](int buf, int ks) {
#pragma unroll
    for (int c = wid; c < 8; c += NWAVES) {
      const unsigned short* gp = Ah + (size_t)(m0 + lane) * K + ks * 64 + c * 8;
      gload_lds16(gp, &smem[buf][c * 1024 + lane * 16]);
    }
  };

  stage(0, 0);
  int cur = 0;
  for (int ks = 0; ks < KSTEPS; ++ks) {
    __syncthreads();   // stage(cur) complete; buffers handed off
    short8v bh[2][4];
#pragma unroll
    for (int hh = 0; hh < 2; ++hh)
#pragma unroll
      for (int ni = 0; ni < 4; ++ni) {
        int kt = ks * 2 + hh;
        size_t off = (((size_t)(ntile0 + ni) * KT32 + kt) * 64 + lane) * 8;
        bh[hh][ni] = *(const short8v*)(Bh + off);
      }
    if (ks + 1 < KSTEPS) stage(cur ^ 1, ks + 1);
    short8v ah[2][MI];
#pragma unroll
    for (int hh = 0; hh < 2; ++hh)
#pragma unroll
      for (int mi = 0; mi < MI; ++mi) {
        int row = wm * MI * 16 + mi * 16 + ar;
        int c = hh * 4 + cchunk;
        ah[hh][mi] = *(const short8v*)&smem[cur][c * 1024 + row * 16];
      }
#pragma unroll
    for (int hh = 0; hh < 2; ++hh)
#pragma unroll
      for (int mi = 0; mi < MI; ++mi)
#pragma unroll
        for (int ni = 0; ni < 4; ++ni)
          acc[mi][ni] = __builtin_amdgcn_mfma_f32_16x16x32_bf16(ah[hh][mi], bh[hh][ni], acc[mi][ni], 0, 0, 0);
    cur ^= 1;
  }

  const int cc = lane & 15;
#pragma unroll
  for (int mi = 0; mi < MI; ++mi) {
    int rowb = m0 + wm * MI * 16 + mi * 16 + ((lane >> 4) << 2);
#pragma unroll
    for (int r = 0; r < 4; ++r) {
      int row = rowb + r;
      if (row < M) {
#pragma unroll
        for (int ni = 0; ni < 4; ++ni)
          C[(size_t)row * Nw + n0 + ni * 16 + cc] = f2bf(acc[mi][ni][r]);
      }
    }
  }

  // fused attention-logit epilogue (bf16-rounded h = downstream values)
  const int head = (HEADS == 4) ? gn : 0;
  float as_[4], ad_[4];
#pragma unroll
  for (int ni = 0; ni < 4; ++ni) {
    as_[ni] = a_s[head * 64 + ni * 16 + cc];
    ad_[ni] = a_d[head * 64 + ni * 16 + cc];
  }
#pragma unroll
  for (int mi = 0; mi < MI; ++mi) {
#pragma unroll
    for (int r = 0; r < 4; ++r) {
      float h0 = bf2f(f2bf(acc[mi][0][r]));
      float h1 = bf2f(f2bf(acc[mi][1][r]));
      float h2 = bf2f(f2bf(acc[mi][2][r]));
      float h3 = bf2f(f2bf(acc[mi][3][r]));
      float ps = h0 * as_[0] + h1 * as_[1] + h2 * as_[2] + h3 * as_[3];
      float pd = h0 * ad_[0] + h1 * ad_[1] + h2 * ad_[2] + h3 * ad_[3];
#pragma unroll
      for (int off = 1; off < 16; off <<= 1) {
        ps += __shfl_xor(ps, off);
        pd += __shfl_xor(pd, off);
      }
      int row = m0 + wm * MI * 16 + mi * 16 + ((lane >> 4) << 2) + r;
      if (cc == 0 && row < M) {
        al_s[row * HEADS + head] = ps;
        al_d[row * HEADS + head] = pd;
      }
    }
  }
}

// ---------------- CSR build ----------------
__global__ void count_kernel(const int* __restrict__ dst, int E, int Etot, int* __restrict__ counts)
{
  int e = blockIdx.x * 256 + threadIdx.x;
  if (e >= Etot) return;
  int d = (e < E) ? dst[e] : (e - E);
  atomicAdd(&counts[d], 1);
}

__global__ void block_sum_kernel(const int* __restrict__ counts, int N, int* __restrict__ bsums)
{
  __shared__ int sd[256];
  int i = blockIdx.x * 256 + threadIdx.x;
  sd[threadIdx.x] = (i < N) ? counts[i] : 0;
  __syncthreads();
  for (int off = 128; off; off >>= 1) {
    if (threadIdx.x < off) sd[threadIdx.x] += sd[threadIdx.x + off];
    __syncthreads();
  }
  if (threadIdx.x == 0) bsums[blockIdx.x] = sd[0];
}

__global__ void scan_bsums_kernel(int* bsums, int nb)
{
  __shared__ int sd[256];
  int t = threadIdx.x;
  int v = (t < nb) ? bsums[t] : 0;
  sd[t] = v;
  __syncthreads();
  for (int off = 1; off < 256; off <<= 1) {
    int x = (t >= off) ? sd[t - off] : 0;
    __syncthreads();
    sd[t] += x;
    __syncthreads();
  }
  if (t < nb) bsums[t] = sd[t] - v;  // exclusive
}

__global__ void scan_write_kernel(const int* __restrict__ counts, int N,
                                  const int* __restrict__ bsums, int* __restrict__ rowStart, int Etot)
{
  __shared__ int sd[256];
  int i = blockIdx.x * 256 + threadIdx.x;
  int v = (i < N) ? counts[i] : 0;
  sd[threadIdx.x] = v;
  __syncthreads();
  for (int off = 1; off < 256; off <<= 1) {
    int x = (threadIdx.x >= off) ? sd[threadIdx.x - off] : 0;
    __syncthreads();
    sd[threadIdx.x] += x;
    __syncthreads();
  }
  if (i < N) rowStart[i] = bsums[blockIdx.x] + sd[threadIdx.x] - v;  // exclusive
  if (i == N - 1) rowStart[N] = Etot;
}

__global__ void fill_kernel(const int* __restrict__ src, const int* __restrict__ dst,
                            int E, int Etot, const int* __restrict__ rowStart,
                            int* __restrict__ cursor, int* __restrict__ csrSrc)
{
  int e = blockIdx.x * 256 + threadIdx.x;
  if (e >= Etot) return;
  int s, d;
  if (e < E) { s = src[e]; d = dst[e]; } else { s = d = e - E; }
  int pos = rowStart[d] + atomicAdd(&cursor[d], 1);
  csrSrc[pos] = s;
}

// ---------------- fused aggregation, 4-head layers (bf16 out) ----------------
// 2 edges per memory instruction, 2-deep ILP: lane = 32*sub + c.
__global__ __launch_bounds__(256) void aggregate_fused4(
    const unsigned short* __restrict__ h16,
    const float* __restrict__ als, const float* __restrict__ ald,
    const int* __restrict__ csrSrc, const int* __restrict__ rowStart,
    unsigned short* __restrict__ outp, int N)
{
  __shared__ float ldsW[4][256];
  const int wl = threadIdx.x >> 6;
  int wid = blockIdx.x * 4 + wl;
  if (wid >= N) return;
  const int lane = threadIdx.x & 63;
  const int sub = lane >> 5, c = lane & 31;   // feature slice c*8..c*8+7
  const int head = c >> 3;
  const int start = rowStart[wid], end = rowStart[wid + 1];

  float4 adv = ((const float4*)ald)[wid];
  float acc[8] = {};
  float wsum = 0.f;

  for (int base = start; base < end; base += 64) {
    int cnt = end - base; if (cnt > 64) cnt = 64;
    int s_l = 0;
    if (lane < cnt) {
      s_l = csrSrc[base + lane];
      float4 av = ((const float4*)als)[s_l];
      float4 w4;
      w4.x = exp_lrelu(av.x + adv.x);
      w4.y = exp_lrelu(av.y + adv.y);
      w4.z = exp_lrelu(av.z + adv.z);
      w4.w = exp_lrelu(av.w + adv.w);
      *(float4*)&ldsW[wl][lane * 4] = w4;
    }
    for (int i = 0; i < cnt; i += 4) {
      int e0 = i + sub, e1 = i + 2 + sub;     // <= 63
      int s0 = __shfl(s_l, e0);
      int s1 = __shfl(s_l, e1);
      float w0 = (e0 < cnt) ? ldsW[wl][e0 * 4 + head] : 0.f;
      float w1 = (e1 < cnt) ? ldsW[wl][e1 * 4 + head] : 0.f;
      short8v r0 = *(const short8v*)(h16 + (size_t)s0 * 256 + c * 8);
      short8v r1 = *(const short8v*)(h16 + (size_t)s1 * 256 + c * 8);
      wsum += w0 + w1;
#pragma unroll
      for (int q = 0; q < 8; ++q)
        acc[q] = fmaf(w0, bf2f((unsigned short)r0[q]), acc[q]);
#pragma unroll
      for (int q = 0; q < 8; ++q)
        acc[q] = fmaf(w1, bf2f((unsigned short)r1[q]), acc[q]);
    }
  }
  // merge the two sub-groups (partner lane has same c)
#pragma unroll
  for (int q = 0; q < 8; ++q) acc[q] += __shfl_xor(acc[q], 32);
  wsum += __shfl_xor(wsum, 32);

  if (sub == 0) {
    float inv = 1.0f / wsum;
    short8v o;
#pragma unroll
    for (int q = 0; q < 8; ++q) o[q] = (short)f2bf(acc[q] * inv);
    *(short8v*)(outp + (size_t)wid * 256 + c * 8) = o;
  }
}

// ---------------- layer-3 aggregation + bias + ELU (fp32 out) ----------------
// 4 edges per memory instruction, 2-deep ILP: lane = 16*sub + c.
__global__ __launch_bounds__(256) void aggregate3_kernel(
    const unsigned short* __restrict__ h16,
    const float* __restrict__ als, const float* __restrict__ ald,
    const int* __restrict__ csrSrc, const int* __restrict__ rowStart,
    const float* __restrict__ b3, float* __restrict__ outp, int N)
{
  __shared__ float ldsW[4][64];
  const int t = threadIdx.x;
  const int wl = t >> 6, lane = t & 63;
  const int sub = lane >> 4, c = lane & 15;   // feature slice c*4..c*4+3
  int wid = blockIdx.x * 4 + wl;
  if (wid >= N) return;
  const int start = rowStart[wid], end = rowStart[wid + 1];
  const float ad0 = ald[wid];
  const float4 b3q = ((const float4*)b3)[c];

  float a0 = 0.f, a1 = 0.f, a2 = 0.f, a3 = 0.f, wsum = 0.f;
  for (int base = start; base < end; base += 64) {
    int cnt = end - base; if (cnt > 64) cnt = 64;
    int s_l = 0;
    if (lane < cnt) {
      s_l = csrSrc[base + lane];
      ldsW[wl][lane] = exp_lrelu(als[s_l] + ad0);
    }
    for (int i = 0; i < cnt; i += 8) {
      int e0 = i + sub, e1 = i + 4 + sub;     // <= 63
      int s0 = __shfl(s_l, e0);
      int s1 = __shfl(s_l, e1);
      float w0 = (e0 < cnt) ? ldsW[wl][e0] : 0.f;
      float w1 = (e1 < cnt) ? ldsW[wl][e1] : 0.f;
      ushort4 r0 = ((const ushort4*)(h16 + (size_t)s0 * 64))[c];
      ushort4 r1 = ((const ushort4*)(h16 + (size_t)s1 * 64))[c];
      wsum += w0 + w1;
      a0 = fmaf(w0, bf2f(r0.x), a0); a0 = fmaf(w1, bf2f(r1.x), a0);
      a1 = fmaf(w0, bf2f(r0.y), a1); a1 = fmaf(w1, bf2f(r1.y), a1);
      a2 = fmaf(w0, bf2f(r0.z), a2); a2 = fmaf(w1, bf2f(r1.z), a2);
      a3 = fmaf(w0, bf2f(r0.w), a3); a3 = fmaf(w1, bf2f(r1.w), a3);
    }
  }
  // merge the four sub-groups (partner lanes share c)
  a0 += __shfl_xor(a0, 16); a1 += __shfl_xor(a1, 16);
  a2 += __shfl_xor(a2, 16); a3 += __shfl_xor(a3, 16);
  wsum += __shfl_xor(wsum, 16);
  a0 += __shfl_xor(a0, 32); a1 += __shfl_xor(a1, 32);
  a2 += __shfl_xor(a2, 32); a3 += __shfl_xor(a3, 32);
  wsum += __shfl_xor(wsum, 32);

  if (sub == 0) {
    float inv = 1.0f / wsum;
    float o0 = elu_fast(a0 * inv + b3q.x);
    float o1 = elu_fast(a1 * inv + b3q.y);
    float o2 = elu_fast(a2 * inv + b3q.z);
    float o3 = elu_fast(a3 * inv + b3q.w);
    *(float4*)(outp + (size_t)wid * 64 + c * 4) = make_float4(o0, o1, o2, o3);
  }
}

// ---------------- MLP head: thread-per-node, LDS weight broadcast ----------------
__global__ __launch_bounds__(256) void mlp_kernel(const float* __restrict__ h,
                           const float* __restrict__ fw1,
                           const float* __restrict__ fb1, const float* __restrict__ fw2,
                           const float* __restrict__ fb2, float* __restrict__ out, int N)
{
  __shared__ float w1s[64][32];
  __shared__ float w2s[32][2];
  __shared__ float b1s[32];
  const int t = threadIdx.x;
  for (int i = t; i < 64 * 32; i += 256) w1s[i >> 5][i & 31] = fw1[i];
  if (t < 64) w2s[t >> 1][t & 1] = fw2[t];
  if (t < 32) b1s[t] = fb1[t];
  __syncthreads();

  int n = blockIdx.x * 256 + t;
  if (n >= N) return;

  float hv[64];
#pragma unroll
  for (int k4 = 0; k4 < 16; ++k4) {
    float4 v = *(const float4*)(h + (size_t)n * 64 + k4 * 4);
    hv[k4 * 4 + 0] = v.x; hv[k4 * 4 + 1] = v.y;
    hv[k4 * 4 + 2] = v.z; hv[k4 * 4 + 3] = v.w;
  }
  float hid[32];
#pragma unroll
  for (int j = 0; j < 32; ++j) hid[j] = b1s[j];
#pragma unroll
  for (int k = 0; k < 64; ++k) {
    float hk = hv[k];
#pragma unroll
    for (int jb = 0; jb < 8; ++jb) {
      float4 wv = *(const float4*)&w1s[k][jb * 4];
      hid[jb * 4 + 0] = fmaf(hk, wv.x, hid[jb * 4 + 0]);
      hid[jb * 4 + 1] = fmaf(hk, wv.y, hid[jb * 4 + 1]);
      hid[jb * 4 + 2] = fmaf(hk, wv.z, hid[jb * 4 + 2]);
      hid[jb * 4 + 3] = fmaf(hk, wv.w, hid[jb * 4 + 3]);
    }
  }
  float p0 = fb2[0], p1 = fb2[1];
#pragma unroll
  for (int j = 0; j < 32; ++j) {
    float r = fmaxf(hid[j], 0.f);
    p0 = fmaf(r, w2s[j][0], p0);
    p1 = fmaf(r, w2s[j][1], p1);
  }
  *(float2*)(out + (size_t)n * 2) = make_float2(p0, p1);
}

// ---------------- batch norm stats (deterministic partials, two dispatches) ----
__global__ __launch_bounds__(256) void bn_stats_kernel(const unsigned short* __restrict__ x, int N,
                                float* __restrict__ partials)   // [128][512]
{
  const int wid = threadIdx.x >> 6, lane = threadIdx.x & 63;
  const int gw = blockIdx.x * 4 + wid;
  const int tw = gridDim.x * 4;
  float4 s = make_float4(0.f, 0.f, 0.f, 0.f);
  float4 q = make_float4(0.f, 0.f, 0.f, 0.f);
#pragma unroll 4
  for (int r = gw; r < N; r += tw) {
    ushort4 u = ((const ushort4*)(x + (size_t)r * 256))[lane];
    float v0 = bf2f(u.x), v1 = bf2f(u.y), v2 = bf2f(u.z), v3 = bf2f(u.w);
    s.x += v0; s.y += v1; s.z += v2; s.w += v3;
    q.x = fmaf(v0, v0, q.x); q.y = fmaf(v1, v1, q.y);
    q.z = fmaf(v2, v2, q.z); q.w = fmaf(v3, v3, q.w);
  }
  __shared__ float ls[4][512];
  *(float4*)&ls[wid][lane * 4] = s;
  *(float4*)&ls[wid][256 + lane * 4] = q;
  __syncthreads();
  const int t = threadIdx.x;
  float a = ls[0][t] + ls[1][t] + ls[2][t] + ls[3][t];
  float b = ls[0][t + 256] + ls[1][t + 256] + ls[2][t + 256] + ls[3][t + 256];
  partials[blockIdx.x * 512 + t] = a;
  partials[blockIdx.x * 512 + 256 + t] = b;
}

__global__ void bn_final_kernel(const float* __restrict__ partials, int nblk,
                                const float* __restrict__ g, const float* __restrict__ be,
                                int N, float* __restrict__ scale, float* __restrict__ shift)
{
  int f = threadIdx.x;
  float s = 0.f, q = 0.f;
#pragma unroll 8
  for (int b = 0; b < nblk; ++b) {
    s += partials[b * 512 + f];
    q += partials[b * 512 + 256 + f];
  }
  float mu = s / N;
  float var = q / N - mu * mu;
  float rs = rsqrtf(var + 1e-5f);
  float sc = g[f] * rs;
  scale[f] = sc;
  shift[f] = be[f] - mu * sc;
}

// ---------------- host ----------------
extern "C" void kernel_launch(void* const* d_in, const int* in_sizes, int n_in,
                              void* d_out, int out_size, void* d_ws, size_t ws_size,
                              hipStream_t stream)
{
  const float* x   = (const float*)d_in[0];
  const int*   ei  = (const int*)d_in[1];
  const float* W1  = (const float*)d_in[2];
  const float* a1s = (const float*)d_in[3];
  const float* a1d = (const float*)d_in[4];
  const float* W2  = (const float*)d_in[6];
  const float* a2s = (const float*)d_in[7];
  const float* a2d = (const float*)d_in[8];
  const float* W3  = (const float*)d_in[10];
  const float* a3s = (const float*)d_in[11];
  const float* a3d = (const float*)d_in[12];
  const float* b3  = (const float*)d_in[13];
  const float* g1  = (const float*)d_in[14];
  const float* be1 = (const float*)d_in[15];
  const float* g2  = (const float*)d_in[16];
  const float* be2 = (const float*)d_in[17];
  const float* fw1 = (const float*)d_in[18];
  const float* fb1 = (const float*)d_in[19];
  const float* fw2 = (const float*)d_in[20];
  const float* fb2 = (const float*)d_in[21];
  float* out = (float*)d_out;

  const int F = 128;
  const int N = in_sizes[0] / F;
  const int E = in_sizes[1] / 2;
  const int Etot = E + N;
  const int* srcIdx = ei;
  const int* dstIdx = ei + E;

  char* w = (char*)d_ws;
  auto alloc = [&](size_t bytes) -> void* {
    void* p = (void*)w;
    w += (bytes + 255) & ~(size_t)255;
    return p;
  };
  unsigned short* h16  = (unsigned short*)alloc((size_t)N * 256 * 2);
  unsigned short* act16= (unsigned short*)alloc((size_t)N * 256 * 2);
  unsigned short* aBf  = (unsigned short*)alloc((size_t)N * 256 * 2);
  float* actf    = (float*)alloc((size_t)N * 64 * 4);
  float* als     = (float*)alloc((size_t)N * 4 * 4);
  float* ald     = (float*)alloc((size_t)N * 4 * 4);
  const size_t cntPad = ((size_t)N * 4 + 255) & ~(size_t)255;
  int*   counts  = (int*)alloc((size_t)N * 4);
  int*   cursor  = (int*)alloc((size_t)N * 4);     // contiguous after counts
  int*   rowStart= (int*)alloc((size_t)(N + 1) * 4);
  int*   csrSrc  = (int*)alloc((size_t)Etot * 4);
  int*   bsums   = (int*)alloc((size_t)((N + 255) / 256) * 4);
  float* partials= (float*)alloc((size_t)128 * 512 * 4);
  float* scale1  = (float*)alloc(256 * 4);
  float* shift1  = (float*)alloc(256 * 4);
  float* scale2  = (float*)alloc(256 * 4);
  float* shift2  = (float*)alloc(256 * 4);
  unsigned short* w1h = (unsigned short*)alloc((size_t)128 * 256 * 2);
  unsigned short* w2h = (unsigned short*)alloc((size_t)256 * 256 * 2);
  unsigned short* w3h = (unsigned short*)alloc((size_t)256 * 64 * 2);
  (void)alloc(65536);   // slack for OOB staging reads of last GEMM block

  const int nb = (N + 255) / 256;
  const int ebk = (Etot + 255) / 256;
  const int aggBlocks = (N + 3) / 4;

  // ---- weight prep (one dispatch for all three) ----
  const int wtot = 128 * 256 + 256 * 256 + 256 * 64;
  wprep_all_kernel<<<(wtot + 255) / 256, 256, 0, stream>>>(W1, w1h, W2, w2h, W3, w3h);

  // ---- CSR build ----
  hipMemsetAsync(counts, 0, cntPad + (size_t)N * 4, stream);   // counts + cursor
  count_kernel<<<ebk, 256, 0, stream>>>(dstIdx, E, Etot, counts);
  block_sum_kernel<<<nb, 256, 0, stream>>>(counts, N, bsums);
  scan_bsums_kernel<<<1, 256, 0, stream>>>(bsums, nb);
  scan_write_kernel<<<nb, 256, 0, stream>>>(counts, N, bsums, rowStart, Etot);
  fill_kernel<<<ebk, 256, 0, stream>>>(srcIdx, dstIdx, E, Etot, rowStart, cursor, csrSrc);

  dim3 g12((N + 63) / 64, 2);      // layers 1,2: MI=4,WM=1,WN=2 -> BM=64,BN=128
  dim3 g3((N + 63) / 64, 1);       // layer 3:   MI=2,WM=2,WN=1 -> BM=64,BN=64

  // ---- GAT layer 1 ----
  split_kernel<<<2048, 256, 0, stream>>>(x, aBf, (size_t)N * 128 / 4);
  gemm_al<4, 1, 2, 2, 4><<<g12, 128, 0, stream>>>(aBf, w1h, a1s, a1d, h16, als, ald, N);
  aggregate_fused4<<<aggBlocks, 256, 0, stream>>>(h16, als, ald, csrSrc, rowStart, act16, N);
  bn_stats_kernel<<<128, 256, 0, stream>>>(act16, N, partials);
  bn_final_kernel<<<1, 256, 0, stream>>>(partials, 128, g1, be1, N, scale1, shift1);

  // ---- GAT layer 2 ----
  bnsplit_kernel<<<2048, 256, 0, stream>>>(act16, scale1, shift1, aBf, (size_t)N * 64);
  gemm_al<4, 1, 2, 4, 4><<<g12, 128, 0, stream>>>(aBf, w2h, a2s, a2d, h16, als, ald, N);
  aggregate_fused4<<<aggBlocks, 256, 0, stream>>>(h16, als, ald, csrSrc, rowStart, act16, N);
  bn_stats_kernel<<<128, 256, 0, stream>>>(act16, N, partials);
  bn_final_kernel<<<1, 256, 0, stream>>>(partials, 128, g2, be2, N, scale2, shift2);

  // ---- GAT layer 3 ----
  bnsplit_kernel<<<2048, 256, 0, stream>>>(act16, scale2, shift2, aBf, (size_t)N * 64);
  gemm_al<2, 2, 1, 4, 1><<<g3, 128, 0, stream>>>(aBf, w3h, a3s, a3d, h16, als, ald, N);
  aggregate3_kernel<<<aggBlocks, 256, 0, stream>>>(h16, als, ald, csrSrc, rowStart, b3, actf, N);

  // ---- MLP head ----
  mlp_kernel<<<(N + 255) / 256, 256, 0, stream>>>(actf, fw1, fb1, fw2, fb2, out, N);
}

// Round 20
// 295.451 us; speedup vs baseline: 1.0564x; 1.0078x over previous
//
#include <hip/hip_runtime.h>
#include <math.h>
#include <stdint.h>

typedef __attribute__((ext_vector_type(8))) short short8v;
typedef __attribute__((ext_vector_type(4))) float float4v;

__device__ __forceinline__ float bf2f(unsigned short u) {
  return __uint_as_float((unsigned int)u << 16);
}
__device__ __forceinline__ unsigned short f2bf(float f) {   // RNE
  unsigned int u = __float_as_uint(f);
  unsigned int r = (u + 0x7FFFu + ((u >> 16) & 1u)) >> 16;
  return (unsigned short)r;
}
__device__ __forceinline__ float exp_lrelu(float x) {
  x = x > 0.f ? x : 0.2f * x;
  return __expf(x);     // fast exp; softmax shift-invariant: max skipped
}
__device__ __forceinline__ float elu_fast(float x) {
  return x > 0.f ? x : __expf(x) - 1.f;
}

typedef __attribute__((address_space(3))) void lds_void;
typedef const __attribute__((address_space(1))) void glb_void;
__device__ __forceinline__ void gload_lds16(const void* g, void* l) {
  __builtin_amdgcn_global_load_lds((glb_void*)g, (lds_void*)l, 16, 0, 0);
}

// ---------------- weight prep (all 3 weights in one dispatch) ----------------
__device__ __forceinline__ void wprep_one(const float* W, unsigned short* Wh,
                                          int t, int K, int Nw)
{
  int i = t & 7;
  int lane = (t >> 3) & 63;
  int frag = t >> 9;
  int ktiles = K >> 5;
  int n_tile = frag / ktiles, k_tile = frag - n_tile * ktiles;
  int k = k_tile * 32 + ((lane >> 4) << 3) + i;
  int n = (n_tile << 4) + (lane & 15);
  Wh[t] = f2bf(W[(size_t)k * Nw + n]);
}

__global__ void wprep_all_kernel(const float* __restrict__ W1, unsigned short* __restrict__ w1h,
                                 const float* __restrict__ W2, unsigned short* __restrict__ w2h,
                                 const float* __restrict__ W3, unsigned short* __restrict__ w3h)
{
  int t = blockIdx.x * 256 + threadIdx.x;
  const int s1 = 128 * 256, s2 = 256 * 256, s3 = 256 * 64;
  if (t < s1) { wprep_one(W1, w1h, t, 128, 256); return; }
  t -= s1;
  if (t < s2) { wprep_one(W2, w2h, t, 256, 256); return; }
  t -= s2;
  if (t < s3) { wprep_one(W3, w3h, t, 256, 64); }
}

// ---------------- A-side: x fp32 -> bf16 (RNE) ----------------
__global__ __launch_bounds__(256) void split_kernel(const float* __restrict__ in,
    unsigned short* __restrict__ hi, size_t n4)
{
  size_t i0 = (size_t)blockIdx.x * 256 + threadIdx.x;
  size_t stride = (size_t)gridDim.x * 256;
  for (size_t idx = i0; idx < n4; idx += stride) {
    float4 v = ((const float4*)in)[idx];
    ushort4 h;
    h.x = f2bf(v.x); h.y = f2bf(v.y); h.z = f2bf(v.z); h.w = f2bf(v.w);
    ((ushort4*)hi)[idx] = h;
  }
}

// BN + ELU -> bf16 (RNE), reading bf16 act
__global__ __launch_bounds__(256) void bnsplit_kernel(const unsigned short* __restrict__ act,
    const float* __restrict__ scale, const float* __restrict__ shift,
    unsigned short* __restrict__ hi, size_t nchunks)
{
  size_t i0 = (size_t)blockIdx.x * 256 + threadIdx.x;
  size_t stride = (size_t)gridDim.x * 256;
  for (size_t idx = i0; idx < nchunks; idx += stride) {
    ushort4 u = ((const ushort4*)act)[idx];
    int f = (int)((idx * 4) & 255);
    float4 sc = *(const float4*)(scale + f);
    float4 sh = *(const float4*)(shift + f);
    float v0 = elu_fast(fmaf(bf2f(u.x), sc.x, sh.x));
    float v1 = elu_fast(fmaf(bf2f(u.y), sc.y, sh.y));
    float v2 = elu_fast(fmaf(bf2f(u.z), sc.z, sh.z));
    float v3 = elu_fast(fmaf(bf2f(u.w), sc.w, sh.w));
    ushort4 h;
    h.x = f2bf(v0); h.y = f2bf(v1); h.z = f2bf(v2); h.w = f2bf(v3);
    ((ushort4*)hi)[idx] = h;
  }
}

// ---------------- single-bf16 MFMA GEMM + fused al epilogue ----------------
// LDS-staged A (double-buffered global_load_lds) + register double-buffered B:
// B for step ks+1 is issued alongside stage(ks+1); the next barrier's implicit
// vmcnt(0) drain resolves both -> no exposed B latency in the MFMA phase.
template<int MI, int WM, int WN, int KSTEPS, int HEADS>
__global__ __launch_bounds__(128) void gemm_al(
    const unsigned short* __restrict__ Ah, const unsigned short* __restrict__ Bh,
    const float* __restrict__ a_s, const float* __restrict__ a_d,
    unsigned short* __restrict__ C, float* __restrict__ al_s, float* __restrict__ al_d,
    int M)
{
  constexpr int NWAVES = WM * WN;            // 2
  constexpr int BM = WM * MI * 16;           // 64
  constexpr int TILEB = BM * 64 * 2;         // 8 KB per buffer
  constexpr int Nw = HEADS * 64;
  constexpr int K = KSTEPS * 64;
  constexpr int KT32 = KSTEPS * 2;
  __shared__ __align__(16) unsigned char smem[2][TILEB];

  const int wid = threadIdx.x >> 6, lane = threadIdx.x & 63;
  const int wm = wid / WN, wn = wid % WN;
  const int gn = blockIdx.y * WN + wn;       // global 64-col tile index
  const int m0 = blockIdx.x * BM;
  const int n0 = gn * 64;
  const int ar = lane & 15;
  const int cchunk = lane >> 4;
  const int ntile0 = n0 >> 4;

  float4v acc[MI][4];
#pragma unroll
  for (int mi = 0; mi < MI; ++mi)
#pragma unroll
    for (int ni = 0; ni < 4; ++ni)
      acc[mi][ni] = (float4v){0.f, 0.f, 0.f, 0.f};

  auto stage = [&](int buf, int ks) {
#pragma unroll
    for (int c = wid; c < 8; c += NWAVES) {
      const unsigned short* gp = Ah + (size_t)(m0 + lane) * K + ks * 64 + c * 8;
      gload_lds16(gp, &smem[buf][c * 1024 + lane * 16]);
    }
  };
  auto loadB = [&](short8v (&b)[2][4], int ks) {
#pragma unroll
    for (int hh = 0; hh < 2; ++hh)
#pragma unroll
      for (int ni = 0; ni < 4; ++ni) {
        int kt = ks * 2 + hh;
        size_t off = (((size_t)(ntile0 + ni) * KT32 + kt) * 64 + lane) * 8;
        b[hh][ni] = *(const short8v*)(Bh + off);
      }
  };

  stage(0, 0);
  short8v bh[2][4];
  loadB(bh, 0);
  int cur = 0;
#pragma unroll
  for (int ks = 0; ks < KSTEPS; ++ks) {
    __syncthreads();   // drains stage(cur) AND the B prefetch for this step
    if (ks + 1 < KSTEPS) stage(cur ^ 1, ks + 1);
    short8v bhn[2][4];
    if (ks + 1 < KSTEPS) loadB(bhn, ks + 1);   // in flight across next barrier
    short8v ah[2][MI];
#pragma unroll
    for (int hh = 0; hh < 2; ++hh)
#pragma unroll
      for (int mi = 0; mi < MI; ++mi) {
        int row = wm * MI * 16 + mi * 16 + ar;
        int c = hh * 4 + cchunk;
        ah[hh][mi] = *(const short8v*)&smem[cur][c * 1024 + row * 16];
      }
#pragma unroll
    for (int hh = 0; hh < 2; ++hh)
#pragma unroll
      for (int mi = 0; mi < MI; ++mi)
#pragma unroll
        for (int ni = 0; ni < 4; ++ni)
          acc[mi][ni] = __builtin_amdgcn_mfma_f32_16x16x32_bf16(ah[hh][mi], bh[hh][ni], acc[mi][ni], 0, 0, 0);
    if (ks + 1 < KSTEPS) {
#pragma unroll
      for (int hh = 0; hh < 2; ++hh)
#pragma unroll
        for (int ni = 0; ni < 4; ++ni) bh[hh][ni] = bhn[hh][ni];   // SSA rename
    }
    cur ^= 1;
  }

  const int cc = lane & 15;
#pragma unroll
  for (int mi = 0; mi < MI; ++mi) {
    int rowb = m0 + wm * MI * 16 + mi * 16 + ((lane >> 4) << 2);
#pragma unroll
    for (int r = 0; r < 4; ++r) {
      int row = rowb + r;
      if (row < M) {
#pragma unroll
        for (int ni = 0; ni < 4; ++ni)
          C[(size_t)row * Nw + n0 + ni * 16 + cc] = f2bf(acc[mi][ni][r]);
      }
    }
  }

  // fused attention-logit epilogue (bf16-rounded h = downstream values)
  const int head = (HEADS == 4) ? gn : 0;
  float as_[4], ad_[4];
#pragma unroll
  for (int ni = 0; ni < 4; ++ni) {
    as_[ni] = a_s[head * 64 + ni * 16 + cc];
    ad_[ni] = a_d[head * 64 + ni * 16 + cc];
  }
#pragma unroll
  for (int mi = 0; mi < MI; ++mi) {
#pragma unroll
    for (int r = 0; r < 4; ++r) {
      float h0 = bf2f(f2bf(acc[mi][0][r]));
      float h1 = bf2f(f2bf(acc[mi][1][r]));
      float h2 = bf2f(f2bf(acc[mi][2][r]));
      float h3 = bf2f(f2bf(acc[mi][3][r]));
      float ps = h0 * as_[0] + h1 * as_[1] + h2 * as_[2] + h3 * as_[3];
      float pd = h0 * ad_[0] + h1 * ad_[1] + h2 * ad_[2] + h3 * ad_[3];
#pragma unroll
      for (int off = 1; off < 16; off <<= 1) {
        ps += __shfl_xor(ps, off);
        pd += __shfl_xor(pd, off);
      }
      int row = m0 + wm * MI * 16 + mi * 16 + ((lane >> 4) << 2) + r;
      if (cc == 0 && row < M) {
        al_s[row * HEADS + head] = ps;
        al_d[row * HEADS + head] = pd;
      }
    }
  }
}

// ---------------- CSR build ----------------
__global__ void count_kernel(const int* __restrict__ dst, int E, int Etot, int* __restrict__ counts)
{
  int e = blockIdx.x * 256 + threadIdx.x;
  if (e >= Etot) return;
  int d = (e < E) ? dst[e] : (e - E);
  atomicAdd(&counts[d], 1);
}

__global__ void block_sum_kernel(const int* __restrict__ counts, int N, int* __restrict__ bsums)
{
  __shared__ int sd[256];
  int i = blockIdx.x * 256 + threadIdx.x;
  sd[threadIdx.x] = (i < N) ? counts[i] : 0;
  __syncthreads();
  for (int off = 128; off; off >>= 1) {
    if (threadIdx.x < off) sd[threadIdx.x] += sd[threadIdx.x + off];
    __syncthreads();
  }
  if (threadIdx.x == 0) bsums[blockIdx.x] = sd[0];
}

__global__ void scan_bsums_kernel(int* bsums, int nb)
{
  __shared__ int sd[256];
  int t = threadIdx.x;
  int v = (t < nb) ? bsums[t] : 0;
  sd[t] = v;
  __syncthreads();
  for (int off = 1; off < 256; off <<= 1) {
    int x = (t >= off) ? sd[t - off] : 0;
    __syncthreads();
    sd[t] += x;
    __syncthreads();
  }
  if (t < nb) bsums[t] = sd[t] - v;  // exclusive
}

__global__ void scan_write_kernel(const int* __restrict__ counts, int N,
                                  const int* __restrict__ bsums, int* __restrict__ rowStart, int Etot)
{
  __shared__ int sd[256];
  int i = blockIdx.x * 256 + threadIdx.x;
  int v = (i < N) ? counts[i] : 0;
  sd[threadIdx.x] = v;
  __syncthreads();
  for (int off = 1; off < 256; off <<= 1) {
    int x = (threadIdx.x >= off) ? sd[threadIdx.x - off] : 0;
    __syncthreads();
    sd[threadIdx.x] += x;
    __syncthreads();
  }
  if (i < N) rowStart[i] = bsums[blockIdx.x] + sd[threadIdx.x] - v;  // exclusive
  if (i == N - 1) rowStart[N] = Etot;
}

__global__ void fill_kernel(const int* __restrict__ src, const int* __restrict__ dst,
                            int E, int Etot, const int* __restrict__ rowStart,
                            int* __restrict__ cursor, int* __restrict__ csrSrc)
{
  int e = blockIdx.x * 256 + threadIdx.x;
  if (e >= Etot) return;
  int s, d;
  if (e < E) { s = src[e]; d = dst[e]; } else { s = d = e - E; }
  int pos = rowStart[d] + atomicAdd(&cursor[d], 1);
  csrSrc[pos] = s;
}

// ---------------- fused aggregation, 4-head layers (bf16 out) ----------------
// 2 edges per memory instruction, 4-deep ILP: lane = 32*sub + c.
__global__ __launch_bounds__(256) void aggregate_fused4(
    const unsigned short* __restrict__ h16,
    const float* __restrict__ als, const float* __restrict__ ald,
    const int* __restrict__ csrSrc, const int* __restrict__ rowStart,
    unsigned short* __restrict__ outp, int N)
{
  __shared__ float ldsW[4][256];
  const int wl = threadIdx.x >> 6;
  int wid = blockIdx.x * 4 + wl;
  if (wid >= N) return;
  const int lane = threadIdx.x & 63;
  const int sub = lane >> 5, c = lane & 31;   // feature slice c*8..c*8+7
  const int head = c >> 3;
  const int start = rowStart[wid], end = rowStart[wid + 1];

  float4 adv = ((const float4*)ald)[wid];
  float acc[8] = {};
  float wsum = 0.f;

  for (int base = start; base < end; base += 64) {
    int cnt = end - base; if (cnt > 64) cnt = 64;
    int s_l = 0;
    if (lane < cnt) {
      s_l = csrSrc[base + lane];
      float4 av = ((const float4*)als)[s_l];
      float4 w4;
      w4.x = exp_lrelu(av.x + adv.x);
      w4.y = exp_lrelu(av.y + adv.y);
      w4.z = exp_lrelu(av.z + adv.z);
      w4.w = exp_lrelu(av.w + adv.w);
      *(float4*)&ldsW[wl][lane * 4] = w4;
    }
    for (int i = 0; i < cnt; i += 8) {
      int e0 = i + sub, e1 = i + 2 + sub, e2 = i + 4 + sub, e3 = i + 6 + sub;  // <=63
      int s0 = __shfl(s_l, e0);
      int s1 = __shfl(s_l, e1);
      int s2 = __shfl(s_l, e2);
      int s3 = __shfl(s_l, e3);
      float w0 = (e0 < cnt) ? ldsW[wl][e0 * 4 + head] : 0.f;
      float w1 = (e1 < cnt) ? ldsW[wl][e1 * 4 + head] : 0.f;
      float w2 = (e2 < cnt) ? ldsW[wl][e2 * 4 + head] : 0.f;
      float w3 = (e3 < cnt) ? ldsW[wl][e3 * 4 + head] : 0.f;
      short8v r0 = *(const short8v*)(h16 + (size_t)s0 * 256 + c * 8);
      short8v r1 = *(const short8v*)(h16 + (size_t)s1 * 256 + c * 8);
      short8v r2 = *(const short8v*)(h16 + (size_t)s2 * 256 + c * 8);
      short8v r3 = *(const short8v*)(h16 + (size_t)s3 * 256 + c * 8);
      wsum += (w0 + w1) + (w2 + w3);
#pragma unroll
      for (int q = 0; q < 8; ++q)
        acc[q] = fmaf(w0, bf2f((unsigned short)r0[q]), acc[q]);
#pragma unroll
      for (int q = 0; q < 8; ++q)
        acc[q] = fmaf(w1, bf2f((unsigned short)r1[q]), acc[q]);
#pragma unroll
      for (int q = 0; q < 8; ++q)
        acc[q] = fmaf(w2, bf2f((unsigned short)r2[q]), acc[q]);
#pragma unroll
      for (int q = 0; q < 8; ++q)
        acc[q] = fmaf(w3, bf2f((unsigned short)r3[q]), acc[q]);
    }
  }
  // merge the two sub-groups (partner lane has same c)
#pragma unroll
  for (int q = 0; q < 8; ++q) acc[q] += __shfl_xor(acc[q], 32);
  wsum += __shfl_xor(wsum, 32);

  if (sub == 0) {
    float inv = 1.0f / wsum;
    short8v o;
#pragma unroll
    for (int q = 0; q < 8; ++q) o[q] = (short)f2bf(acc[q] * inv);
    *(short8v*)(outp + (size_t)wid * 256 + c * 8) = o;
  }
}

// ---------------- layer-3 aggregation + bias + ELU (fp32 out) ----------------
// 4 edges per memory instruction, 4-deep ILP: lane = 16*sub + c.
__global__ __launch_bounds__(256) void aggregate3_kernel(
    const unsigned short* __restrict__ h16,
    const float* __restrict__ als, const float* __restrict__ ald,
    const int* __restrict__ csrSrc, const int* __restrict__ rowStart,
    const float* __restrict__ b3, float* __restrict__ outp, int N)
{
  __shared__ float ldsW[4][64];
  const int t = threadIdx.x;
  const int wl = t >> 6, lane = t & 63;
  const int sub = lane >> 4, c = lane & 15;   // feature slice c*4..c*4+3
  int wid = blockIdx.x * 4 + wl;
  if (wid >= N) return;
  const int start = rowStart[wid], end = rowStart[wid + 1];
  const float ad0 = ald[wid];
  const float4 b3q = ((const float4*)b3)[c];

  float a0 = 0.f, a1 = 0.f, a2 = 0.f, a3 = 0.f, wsum = 0.f;
  for (int base = start; base < end; base += 64) {
    int cnt = end - base; if (cnt > 64) cnt = 64;
    int s_l = 0;
    if (lane < cnt) {
      s_l = csrSrc[base + lane];
      ldsW[wl][lane] = exp_lrelu(als[s_l] + ad0);
    }
    for (int i = 0; i < cnt; i += 16) {
      int e0 = i + sub, e1 = i + 4 + sub, e2 = i + 8 + sub, e3 = i + 12 + sub;  // <=63
      int s0 = __shfl(s_l, e0);
      int s1 = __shfl(s_l, e1);
      int s2 = __shfl(s_l, e2);
      int s3 = __shfl(s_l, e3);
      float w0 = (e0 < cnt) ? ldsW[wl][e0] : 0.f;
      float w1 = (e1 < cnt) ? ldsW[wl][e1] : 0.f;
      float w2 = (e2 < cnt) ? ldsW[wl][e2] : 0.f;
      float w3 = (e3 < cnt) ? ldsW[wl][e3] : 0.f;
      ushort4 r0 = ((const ushort4*)(h16 + (size_t)s0 * 64))[c];
      ushort4 r1 = ((const ushort4*)(h16 + (size_t)s1 * 64))[c];
      ushort4 r2 = ((const ushort4*)(h16 + (size_t)s2 * 64))[c];
      ushort4 r3 = ((const ushort4*)(h16 + (size_t)s3 * 64))[c];
      wsum += (w0 + w1) + (w2 + w3);
      a0 = fmaf(w0, bf2f(r0.x), a0); a0 = fmaf(w1, bf2f(r1.x), a0);
      a0 = fmaf(w2, bf2f(r2.x), a0); a0 = fmaf(w3, bf2f(r3.x), a0);
      a1 = fmaf(w0, bf2f(r0.y), a1); a1 = fmaf(w1, bf2f(r1.y), a1);
      a1 = fmaf(w2, bf2f(r2.y), a1); a1 = fmaf(w3, bf2f(r3.y), a1);
      a2 = fmaf(w0, bf2f(r0.z), a2); a2 = fmaf(w1, bf2f(r1.z), a2);
      a2 = fmaf(w2, bf2f(r2.z), a2); a2 = fmaf(w3, bf2f(r3.z), a2);
      a3 = fmaf(w0, bf2f(r0.w), a3); a3 = fmaf(w1, bf2f(r1.w), a3);
      a3 = fmaf(w2, bf2f(r2.w), a3); a3 = fmaf(w3, bf2f(r3.w), a3);
    }
  }
  // merge the four sub-groups (partner lanes share c)
  a0 += __shfl_xor(a0, 16); a1 += __shfl_xor(a1, 16);
  a2 += __shfl_xor(a2, 16); a3 += __shfl_xor(a3, 16);
  wsum += __shfl_xor(wsum, 16);
  a0 += __shfl_xor(a0, 32); a1 += __shfl_xor(a1, 32);
  a2 += __shfl_xor(a2, 32); a3 += __shfl_xor(a3, 32);
  wsum += __shfl_xor(wsum, 32);

  if (sub == 0) {
    float inv = 1.0f / wsum;
    float o0 = elu_fast(a0 * inv + b3q.x);
    float o1 = elu_fast(a1 * inv + b3q.y);
    float o2 = elu_fast(a2 * inv + b3q.z);
    float o3 = elu_fast(a3 * inv + b3q.w);
    *(float4*)(outp + (size_t)wid * 64 + c * 4) = make_float4(o0, o1, o2, o3);
  }
}

// ---------------- MLP head: thread-per-node, LDS weight broadcast ----------------
__global__ __launch_bounds__(256) void mlp_kernel(const float* __restrict__ h,
                           const float* __restrict__ fw1,
                           const float* __restrict__ fb1, const float* __restrict__ fw2,
                           const float* __restrict__ fb2, float* __restrict__ out, int N)
{
  __shared__ float w1s[64][32];
  __shared__ float w2s[32][2];
  __shared__ float b1s[32];
  const int t = threadIdx.x;
  for (int i = t; i < 64 * 32; i += 256) w1s[i >> 5][i & 31] = fw1[i];
  if (t < 64) w2s[t >> 1][t & 1] = fw2[t];
  if (t < 32) b1s[t] = fb1[t];
  __syncthreads();

  int n = blockIdx.x * 256 + t;
  if (n >= N) return;

  float hv[64];
#pragma unroll
  for (int k4 = 0; k4 < 16; ++k4) {
    float4 v = *(const float4*)(h + (size_t)n * 64 + k4 * 4);
    hv[k4 * 4 + 0] = v.x; hv[k4 * 4 + 1] = v.y;
    hv[k4 * 4 + 2] = v.z; hv[k4 * 4 + 3] = v.w;
  }
  float hid[32];
#pragma unroll
  for (int j = 0; j < 32; ++j) hid[j] = b1s[j];
#pragma unroll
  for (int k = 0; k < 64; ++k) {
    float hk = hv[k];
#pragma unroll
    for (int jb = 0; jb < 8; ++jb) {
      float4 wv = *(const float4*)&w1s[k][jb * 4];
      hid[jb * 4 + 0] = fmaf(hk, wv.x, hid[jb * 4 + 0]);
      hid[jb * 4 + 1] = fmaf(hk, wv.y, hid[jb * 4 + 1]);
      hid[jb * 4 + 2] = fmaf(hk, wv.z, hid[jb * 4 + 2]);
      hid[jb * 4 + 3] = fmaf(hk, wv.w, hid[jb * 4 + 3]);
    }
  }
  float p0 = fb2[0], p1 = fb2[1];
#pragma unroll
  for (int j = 0; j < 32; ++j) {
    float r = fmaxf(hid[j], 0.f);
    p0 = fmaf(r, w2s[j][0], p0);
    p1 = fmaf(r, w2s[j][1], p1);
  }
  *(float2*)(out + (size_t)n * 2) = make_float2(p0, p1);
}

// ---------------- batch norm stats (deterministic partials, two dispatches) ----
__global__ __launch_bounds__(256) void bn_stats_kernel(const unsigned short* __restrict__ x, int N,
                                float* __restrict__ partials)   // [128][512]
{
  const int wid = threadIdx.x >> 6, lane = threadIdx.x & 63;
  const int gw = blockIdx.x * 4 + wid;
  const int tw = gridDim.x * 4;
  float4 s = make_float4(0.f, 0.f, 0.f, 0.f);
  float4 q = make_float4(0.f, 0.f, 0.f, 0.f);
#pragma unroll 4
  for (int r = gw; r < N; r += tw) {
    ushort4 u = ((const ushort4*)(x + (size_t)r * 256))[lane];
    float v0 = bf2f(u.x), v1 = bf2f(u.y), v2 = bf2f(u.z), v3 = bf2f(u.w);
    s.x += v0; s.y += v1; s.z += v2; s.w += v3;
    q.x = fmaf(v0, v0, q.x); q.y = fmaf(v1, v1, q.y);
    q.z = fmaf(v2, v2, q.z); q.w = fmaf(v3, v3, q.w);
  }
  __shared__ float ls[4][512];
  *(float4*)&ls[wid][lane * 4] = s;
  *(float4*)&ls[wid][256 + lane * 4] = q;
  __syncthreads();
  const int t = threadIdx.x;
  float a = ls[0][t] + ls[1][t] + ls[2][t] + ls[3][t];
  float b = ls[0][t + 256] + ls[1][t + 256] + ls[2][t + 256] + ls[3][t + 256];
  partials[blockIdx.x * 512 + t] = a;
  partials[blockIdx.x * 512 + 256 + t] = b;
}

__global__ void bn_final_kernel(const float* __restrict__ partials, int nblk,
                                const float* __restrict__ g, const float* __restrict__ be,
                                int N, float* __restrict__ scale, float* __restrict__ shift)
{
  int f = threadIdx.x;
  float s = 0.f, q = 0.f;
#pragma unroll 8
  for (int b = 0; b < nblk; ++b) {
    s += partials[b * 512 + f];
    q += partials[b * 512 + 256 + f];
  }
  float mu = s / N;
  float var = q / N - mu * mu;
  float rs = rsqrtf(var + 1e-5f);
  float sc = g[f] * rs;
  scale[f] = sc;
  shift[f] = be[f] - mu * sc;
}

// ---------------- host ----------------
extern "C" void kernel_launch(void* const* d_in, const int* in_sizes, int n_in,
                              void* d_out, int out_size, void* d_ws, size_t ws_size,
                              hipStream_t stream)
{
  const float* x   = (const float*)d_in[0];
  const int*   ei  = (const int*)d_in[1];
  const float* W1  = (const float*)d_in[2];
  const float* a1s = (const float*)d_in[3];
  const float* a1d = (const float*)d_in[4];
  const float* W2  = (const float*)d_in[6];
  const float* a2s = (const float*)d_in[7];
  const float* a2d = (const float*)d_in[8];
  const float* W3  = (const float*)d_in[10];
  const float* a3s = (const float*)d_in[11];
  const float* a3d = (const float*)d_in[12];
  const float* b3  = (const float*)d_in[13];
  const float* g1  = (const float*)d_in[14];
  const float* be1 = (const float*)d_in[15];
  const float* g2  = (const float*)d_in[16];
  const float* be2 = (const float*)d_in[17];
  const float* fw1 = (const float*)d_in[18];
  const float* fb1 = (const float*)d_in[19];
  const float* fw2 = (const float*)d_in[20];
  const float* fb2 = (const float*)d_in[21];
  float* out = (float*)d_out;

  const int F = 128;
  const int N = in_sizes[0] / F;
  const int E = in_sizes[1] / 2;
  const int Etot = E + N;
  const int* srcIdx = ei;
  const int* dstIdx = ei + E;

  char* w = (char*)d_ws;
  auto alloc = [&](size_t bytes) -> void* {
    void* p = (void*)w;
    w += (bytes + 255) & ~(size_t)255;
    return p;
  };
  unsigned short* h16  = (unsigned short*)alloc((size_t)N * 256 * 2);
  unsigned short* act16= (unsigned short*)alloc((size_t)N * 256 * 2);
  unsigned short* aBf  = (unsigned short*)alloc((size_t)N * 256 * 2);
  float* actf    = (float*)alloc((size_t)N * 64 * 4);
  float* als     = (float*)alloc((size_t)N * 4 * 4);
  float* ald     = (float*)alloc((size_t)N * 4 * 4);
  const size_t cntPad = ((size_t)N * 4 + 255) & ~(size_t)255;
  int*   counts  = (int*)alloc((size_t)N * 4);
  int*   cursor  = (int*)alloc((size_t)N * 4);     // contiguous after counts
  int*   rowStart= (int*)alloc((size_t)(N + 1) * 4);
  int*   csrSrc  = (int*)alloc((size_t)Etot * 4);
  int*   bsums   = (int*)alloc((size_t)((N + 255) / 256) * 4);
  float* partials= (float*)alloc((size_t)128 * 512 * 4);
  float* scale1  = (float*)alloc(256 * 4);
  float* shift1  = (float*)alloc(256 * 4);
  float* scale2  = (float*)alloc(256 * 4);
  float* shift2  = (float*)alloc(256 * 4);
  unsigned short* w1h = (unsigned short*)alloc((size_t)128 * 256 * 2);
  unsigned short* w2h = (unsigned short*)alloc((size_t)256 * 256 * 2);
  unsigned short* w3h = (unsigned short*)alloc((size_t)256 * 64 * 2);
  (void)alloc(65536);   // slack for OOB staging reads of last GEMM block

  const int nb = (N + 255) / 256;
  const int ebk = (Etot + 255) / 256;
  const int aggBlocks = (N + 3) / 4;

  // ---- weight prep (one dispatch for all three) ----
  const int wtot = 128 * 256 + 256 * 256 + 256 * 64;
  wprep_all_kernel<<<(wtot + 255) / 256, 256, 0, stream>>>(W1, w1h, W2, w2h, W3, w3h);

  // ---- CSR build ----
  hipMemsetAsync(counts, 0, cntPad + (size_t)N * 4, stream);   // counts + cursor
  count_kernel<<<ebk, 256, 0, stream>>>(dstIdx, E, Etot, counts);
  block_sum_kernel<<<nb, 256, 0, stream>>>(counts, N, bsums);
  scan_bsums_kernel<<<1, 256, 0, stream>>>(bsums, nb);
  scan_write_kernel<<<nb, 256, 0, stream>>>(counts, N, bsums, rowStart, Etot);
  fill_kernel<<<ebk, 256, 0, stream>>>(srcIdx, dstIdx, E, Etot, rowStart, cursor, csrSrc);

  dim3 g12((N + 63) / 64, 2);      // layers 1,2: MI=4,WM=1,WN=2 -> BM=64,BN=128
  dim3 g3((N + 63) / 64, 1);       // layer 3:   MI=2,WM=2,WN=1 -> BM=64,BN=64

  // ---- GAT layer 1 ----
  split_kernel<<<2048, 256, 0, stream>>>(x, aBf, (size_t)N * 128 / 4);
  gemm_al<4, 1, 2, 2, 4><<<g12, 128, 0, stream>>>(aBf, w1h, a1s, a1d, h16, als, ald, N);
  aggregate_fused4<<<aggBlocks, 256, 0, stream>>>(h16, als, ald, csrSrc, rowStart, act16, N);
  bn_stats_kernel<<<128, 256, 0, stream>>>(act16, N, partials);
  bn_final_kernel<<<1, 256, 0, stream>>>(partials, 128, g1, be1, N, scale1, shift1);

  // ---- GAT layer 2 ----
  bnsplit_kernel<<<2048, 256, 0, stream>>>(act16, scale1, shift1, aBf, (size_t)N * 64);
  gemm_al<4, 1, 2, 4, 4><<<g12, 128, 0, stream>>>(aBf, w2h, a2s, a2d, h16, als, ald, N);
  aggregate_fused4<<<aggBlocks, 256, 0, stream>>>(h16, als, ald, csrSrc, rowStart, act16, N);
  bn_stats_kernel<<<128, 256, 0, stream>>>(act16, N, partials);
  bn_final_kernel<<<1, 256, 0, stream>>>(partials, 128, g2, be2, N, scale2, shift2);

  // ---- GAT layer 3 ----
  bnsplit_kernel<<<2048, 256, 0, stream>>>(act16, scale2, shift2, aBf, (size_t)N * 64);
  gemm_al<2, 2, 1, 4, 1><<<g3, 128, 0, stream>>>(aBf, w3h, a3s, a3d, h16, als, ald, N);
  aggregate3_kernel<<<aggBlocks, 256, 0, stream>>>(h16, als, ald, csrSrc, rowStart, b3, actf, N);

  // ---- MLP head ----
  mlp_kernel<<<(N + 255) / 256, 256, 0, stream>>>(actf, fw1, fb1, fw2, fb2, out, N);
}